// Round 11
// baseline (1129.016 us; speedup 1.0000x reference)
//
#include <hip/hip_runtime.h>
#include <hip/hip_bf16.h>

typedef __attribute__((ext_vector_type(8))) short s16x8;
typedef __attribute__((ext_vector_type(4))) float f32x4;
typedef __attribute__((ext_vector_type(16))) float f32x16;
typedef unsigned short u16;
typedef unsigned int u32;
typedef unsigned long long u64;

#define MFMA(a,b,c) __builtin_amdgcn_mfma_f32_16x16x32_bf16(a,b,c,0,0,0)
#define MFMA32(a,b,c) __builtin_amdgcn_mfma_f32_32x32x16_bf16(a,b,c,0,0,0)

constexpr int B_ = 4, T_ = 2048, TKV_ = 512, D_ = 1024, H_ = 16, HD_ = 64;
constexpr int HID_ = 2736, HIDP_ = 2816; // padded to 22*128

__device__ __forceinline__ float bf2f(u16 x) {
    union { float f; u32 u; } c; c.u = ((u32)x) << 16; return c.f;
}
__device__ __forceinline__ u16 f2bf(float f) {
    union { float f; u32 u; } c; c.f = f;
    u32 r = c.u + 0x7fffu + ((c.u >> 16) & 1u);
    return (u16)(r >> 16);
}

__device__ __forceinline__ void gload16(const void* g, void* l) {
    __builtin_amdgcn_global_load_lds(
        (const __attribute__((address_space(1))) u32*)g,
        (__attribute__((address_space(3))) u32*)l, 16, 0, 0);
}

// ---------------- weight transpose + cast:  W[K,N] f32 -> WT[Np,Kp] bf16 (zero-padded)
__global__ __launch_bounds__(256) void wt_cast(const float* __restrict__ W, u16* __restrict__ WT,
                                               int K, int N, int Kp, int Np) {
    __shared__ float t[32][33];
    int tid = threadIdx.x;
    int tx = tid & 31, ty = tid >> 5;
    int n0 = blockIdx.x * 32, k0 = blockIdx.y * 32;
#pragma unroll
    for (int i = 0; i < 4; ++i) {
        int kk = k0 + ty + i * 8, nn = n0 + tx;
        t[ty + i * 8][tx] = (kk < K && nn < N) ? W[(size_t)kk * N + nn] : 0.f;
    }
    __syncthreads();
#pragma unroll
    for (int i = 0; i < 4; ++i) {
        int nn = n0 + ty + i * 8, kk = k0 + tx;
        WT[(size_t)nn * Kp + kk] = f2bf(t[tx][ty + i * 8]);
    }
}

// ---------------- f32 -> bf16 cast (4 elems/thread)
__global__ __launch_bounds__(256) void cast_bf16(const float* __restrict__ in, u16* __restrict__ out, int n4) {
    int i = blockIdx.x * 256 + threadIdx.x;
    if (i >= n4) return;
    float4 v = ((const float4*)in)[i];
    u64 pk = (u64)f2bf(v.x) | ((u64)f2bf(v.y) << 16) | ((u64)f2bf(v.z) << 32) | ((u64)f2bf(v.w) << 48);
    ((u64*)out)[i] = pk;
}

// ---------------- epilogue store helper
__device__ __forceinline__ void gemm_store(void* C, const u16* mul, size_t idx, float v, int mode) {
    if (mode == 0) {
        ((float*)C)[idx] = v;
    } else if (mode == 1) {
        ((u16*)C)[idx] = f2bf(v);
    } else if (mode == 2) {
        float sg = 1.f / (1.f + __expf(-v));
        ((u16*)C)[idx] = f2bf(v * sg);
    } else if (mode == 3) {
        float h = bf2f(mul[idx]);
        ((u16*)C)[idx] = f2bf(v * h);
    } else {
        ((u16*)C)[idx] = f2bf(v * 0.125f);
    }
}

// LDS slot swizzle (T2, rule #21): physical 16B-slot p of row r holds logical
// slot p^(r&7); staged via inverse-permuted GLOBAL source (LDS dest linear for
// global_load_lds); reads apply the same XOR.

// ---------------- GEMM 128x128 tile, 4 waves, SINGLE-buffered (32 KiB LDS), slot-swizzled.
// (r3/r9 proven structure; inter-block overlap hides the stage drain)
__global__ __launch_bounds__(256) void gemm_bf16(const u16* __restrict__ A, const u16* __restrict__ Bt,
                                                 void* __restrict__ C, const u16* __restrict__ mul,
                                                 int M, int N, int K, int mode, int nwg) {
    __shared__ __align__(16) u16 As[128 * 64];
    __shared__ __align__(16) u16 Bs[128 * 64];
    const int tid = threadIdx.x;
    const int lane = tid & 63, wid = tid >> 6;
    const int wr = wid >> 1, wc = wid & 1;
    const int li = lane & 15, g = lane >> 4;

    int bid = (int)blockIdx.x;
    bid = (bid & 7) * (nwg >> 3) + (bid >> 3);

    const int tn = N >> 7;
    const int m0 = (bid / tn) * 128, n0 = (bid % tn) * 128;

    const int rowst = tid >> 3;
    const int colb = (((tid & 7) ^ ((tid >> 3) & 7)) * 16);   // inverse-swizzled source slot
    const char* ga = (const char*)A + ((size_t)(m0 + rowst) * K) * 2 + colb;
    const char* gb = (const char*)Bt + ((size_t)(n0 + rowst) * K) * 2 + colb;
    const size_t rstride = (size_t)32 * K * 2;

    f32x4 acc[4][4] = {};
    const int nt = K >> 6;

    for (int t = 0; t < nt; ++t) {
#pragma unroll
        for (int i = 0; i < 4; ++i) {
            gload16(ga + (size_t)t * 128 + i * rstride, (char*)As + i * 4096 + wid * 1024);
            gload16(gb + (size_t)t * 128 + i * rstride, (char*)Bs + i * 4096 + wid * 1024);
        }
        __syncthreads();
#pragma unroll
        for (int kk = 0; kk < 2; ++kk) {
            s16x8 aF[4], bF[4];
            const int sl = ((kk << 2) | g) ^ (li & 7);
#pragma unroll
            for (int m = 0; m < 4; ++m) aF[m] = *(const s16x8*)&As[(wr * 64 + m * 16 + li) * 64 + sl * 8];
#pragma unroll
            for (int n = 0; n < 4; ++n) bF[n] = *(const s16x8*)&Bs[(wc * 64 + n * 16 + li) * 64 + sl * 8];
#pragma unroll
            for (int m = 0; m < 4; ++m)
#pragma unroll
                for (int n = 0; n < 4; ++n)
                    acc[m][n] = MFMA(aF[m], bF[n], acc[m][n]);
        }
        __syncthreads();
    }

#pragma unroll
    for (int m = 0; m < 4; ++m)
#pragma unroll
        for (int n = 0; n < 4; ++n)
#pragma unroll
            for (int r = 0; r < 4; ++r) {
                size_t row = m0 + wr * 64 + m * 16 + g * 4 + r;
                size_t col = n0 + wc * 64 + n * 16 + li;
                gemm_store(C, mul, row * N + col, acc[m][n][r], mode);
            }
}

// ---------------- DUAL-PANEL GEMM (w13's exact 425-TF structure, generalized):
// stages A once + TWO B panels of the SAME weight (cols n0 and n0+dN);
// computes two 128x128 outputs. 48 KiB LDS, 12 loads/thread/K-tile,
// 2x2 wave grid, two acc sets -- byte-for-byte the gemm_w13 loop.
__global__ __launch_bounds__(256) void gemm_dual(const u16* __restrict__ A, const u16* __restrict__ Bt,
                                                 void* __restrict__ C, const u16* __restrict__ mul,
                                                 int M, int N, int K, int dN, int mode, int nwg) {
    __shared__ __align__(16) u16 As[128 * 64];
    __shared__ __align__(16) u16 B1s[128 * 64];
    __shared__ __align__(16) u16 B2s[128 * 64];
    const int tid = threadIdx.x;
    const int lane = tid & 63, wid = tid >> 6;
    const int wr = wid >> 1, wc = wid & 1;
    const int li = lane & 15, g = lane >> 4;

    int bid = (int)blockIdx.x;
    bid = (bid & 7) * (nwg >> 3) + (bid >> 3);

    const int tn = dN >> 7;
    const int m0 = (bid / tn) * 128, n0 = (bid % tn) * 128;

    const int rowst = tid >> 3;
    const int colb = (((tid & 7) ^ ((tid >> 3) & 7)) * 16);
    const char* ga = (const char*)A + ((size_t)(m0 + rowst) * K) * 2 + colb;
    const char* gb1 = (const char*)Bt + ((size_t)(n0 + rowst) * K) * 2 + colb;
    const char* gb2 = (const char*)Bt + ((size_t)(n0 + dN + rowst) * K) * 2 + colb;
    const size_t rstride = (size_t)32 * K * 2;

    f32x4 acc1[4][4] = {}, acc2[4][4] = {};
    const int nt = K >> 6;

    for (int t = 0; t < nt; ++t) {
#pragma unroll
        for (int i = 0; i < 4; ++i) {
            gload16(ga + (size_t)t * 128 + i * rstride, (char*)As + i * 4096 + wid * 1024);
            gload16(gb1 + (size_t)t * 128 + i * rstride, (char*)B1s + i * 4096 + wid * 1024);
            gload16(gb2 + (size_t)t * 128 + i * rstride, (char*)B2s + i * 4096 + wid * 1024);
        }
        __syncthreads();
#pragma unroll
        for (int kk = 0; kk < 2; ++kk) {
            const int sl = ((kk << 2) | g) ^ (li & 7);
            s16x8 aF[4];
#pragma unroll
            for (int m = 0; m < 4; ++m) aF[m] = *(const s16x8*)&As[(wr * 64 + m * 16 + li) * 64 + sl * 8];
            {   // panel 1
                s16x8 bF[4];
#pragma unroll
                for (int n = 0; n < 4; ++n) bF[n] = *(const s16x8*)&B1s[(wc * 64 + n * 16 + li) * 64 + sl * 8];
#pragma unroll
                for (int m = 0; m < 4; ++m)
#pragma unroll
                    for (int n = 0; n < 4; ++n)
                        acc1[m][n] = MFMA(aF[m], bF[n], acc1[m][n]);
            }
            {   // panel 2
                s16x8 bF[4];
#pragma unroll
                for (int n = 0; n < 4; ++n) bF[n] = *(const s16x8*)&B2s[(wc * 64 + n * 16 + li) * 64 + sl * 8];
#pragma unroll
                for (int m = 0; m < 4; ++m)
#pragma unroll
                    for (int n = 0; n < 4; ++n)
                        acc2[m][n] = MFMA(aF[m], bF[n], acc2[m][n]);
            }
        }
        __syncthreads();
    }

#pragma unroll
    for (int m = 0; m < 4; ++m)
#pragma unroll
        for (int n = 0; n < 4; ++n)
#pragma unroll
            for (int r = 0; r < 4; ++r) {
                size_t row = m0 + wr * 64 + m * 16 + g * 4 + r;
                size_t col = n0 + wc * 64 + n * 16 + li;
                gemm_store(C, mul, row * N + col, acc1[m][n][r], mode);
                gemm_store(C, mul, row * N + col + dN, acc2[m][n][r], mode);
            }
}

// ---------------- fused SwiGLU hidden GEMM: H = silu(A@W1t^T) * (A@W3t^T).
__global__ __launch_bounds__(256) void gemm_w13(const u16* __restrict__ A, const u16* __restrict__ B1t,
                                                const u16* __restrict__ B3t, u16* __restrict__ Hout,
                                                int M, int N, int K, int nwg) {
    __shared__ __align__(16) u16 As[128 * 64];
    __shared__ __align__(16) u16 B1s[128 * 64];
    __shared__ __align__(16) u16 B3s[128 * 64];
    const int tid = threadIdx.x;
    const int lane = tid & 63, wid = tid >> 6;
    const int wr = wid >> 1, wc = wid & 1;
    const int li = lane & 15, g = lane >> 4;

    int bid = (int)blockIdx.x;
    bid = (bid & 7) * (nwg >> 3) + (bid >> 3);

    const int tn = N >> 7;
    const int m0 = (bid / tn) * 128, n0 = (bid % tn) * 128;

    const int rowst = tid >> 3;
    const int colb = (((tid & 7) ^ ((tid >> 3) & 7)) * 16);
    const char* ga = (const char*)A + ((size_t)(m0 + rowst) * K) * 2 + colb;
    const char* gb1 = (const char*)B1t + ((size_t)(n0 + rowst) * K) * 2 + colb;
    const char* gb3 = (const char*)B3t + ((size_t)(n0 + rowst) * K) * 2 + colb;
    const size_t rstride = (size_t)32 * K * 2;

    f32x4 acc1[4][4] = {}, acc3[4][4] = {};
    const int nt = K >> 6;

    for (int t = 0; t < nt; ++t) {
#pragma unroll
        for (int i = 0; i < 4; ++i) {
            gload16(ga + (size_t)t * 128 + i * rstride, (char*)As + i * 4096 + wid * 1024);
            gload16(gb1 + (size_t)t * 128 + i * rstride, (char*)B1s + i * 4096 + wid * 1024);
            gload16(gb3 + (size_t)t * 128 + i * rstride, (char*)B3s + i * 4096 + wid * 1024);
        }
        __syncthreads();
#pragma unroll
        for (int kk = 0; kk < 2; ++kk) {
            const int sl = ((kk << 2) | g) ^ (li & 7);
            s16x8 aF[4];
#pragma unroll
            for (int m = 0; m < 4; ++m) aF[m] = *(const s16x8*)&As[(wr * 64 + m * 16 + li) * 64 + sl * 8];
            {   // W1 product
                s16x8 bF[4];
#pragma unroll
                for (int n = 0; n < 4; ++n) bF[n] = *(const s16x8*)&B1s[(wc * 64 + n * 16 + li) * 64 + sl * 8];
#pragma unroll
                for (int m = 0; m < 4; ++m)
#pragma unroll
                    for (int n = 0; n < 4; ++n)
                        acc1[m][n] = MFMA(aF[m], bF[n], acc1[m][n]);
            }
            {   // W3 product
                s16x8 bF[4];
#pragma unroll
                for (int n = 0; n < 4; ++n) bF[n] = *(const s16x8*)&B3s[(wc * 64 + n * 16 + li) * 64 + sl * 8];
#pragma unroll
                for (int m = 0; m < 4; ++m)
#pragma unroll
                    for (int n = 0; n < 4; ++n)
                        acc3[m][n] = MFMA(aF[m], bF[n], acc3[m][n]);
            }
        }
        __syncthreads();
    }

#pragma unroll
    for (int m = 0; m < 4; ++m)
#pragma unroll
        for (int n = 0; n < 4; ++n)
#pragma unroll
            for (int r = 0; r < 4; ++r) {
                size_t row = m0 + wr * 64 + m * 16 + g * 4 + r;
                size_t col = n0 + wc * 64 + n * 16 + li;
                float h1 = acc1[m][n][r];
                float h3 = acc3[m][n][r];
                float sg = 1.f / (1.f + __expf(-h1));
                Hout[row * N + col] = f2bf(h1 * sg * h3);
            }
}

// ---------------- RoPE in-place on q and k (strided); q additionally scaled by 0.125
__global__ __launch_bounds__(256) void rope_qk(u16* __restrict__ q, u16* __restrict__ k,
                                               const float* __restrict__ fr, int S) {
    size_t idx = (size_t)blockIdx.x * 256 + threadIdx.x; // over B*T*H*(HD/2)
    int i = (int)(idx & 31);
    int h = (int)((idx >> 5) & 15);
    size_t bt = idx >> 9;             // b*T + t
    int t = (int)(bt & (T_ - 1));
    float2 cs = ((const float2*)fr)[t * 32 + i];
    size_t off = bt * (size_t)S + h * 64 + 2 * i;
    {
        u32* p = (u32*)(q + off);
        u32 w = *p;
        float a = bf2f((u16)(w & 0xffff)), b = bf2f((u16)(w >> 16));
        *p = (u32)f2bf((a * cs.x - b * cs.y) * 0.125f) | ((u32)f2bf((a * cs.y + b * cs.x) * 0.125f) << 16);
    }
    {
        u32* p = (u32*)(k + off);
        u32 w = *p;
        float a = bf2f((u16)(w & 0xffff)), b = bf2f((u16)(w >> 16));
        *p = (u32)f2bf(a * cs.x - b * cs.y) | ((u32)f2bf(a * cs.y + b * cs.x) << 16);
    }
}

// ---------------- V transpose: v[B,Tk,*] (stride S) bf16 -> vT[B,H,HD,Tk] bf16
__global__ __launch_bounds__(256) void vtrans(const u16* __restrict__ v, u16* __restrict__ vT,
                                              int Tk, int S) {
    __shared__ u16 tile[32][34];
    int bh = blockIdx.x;
    int t0 = blockIdx.y * 32, d0 = blockIdx.z * 32;
    int b = bh >> 4, h = bh & 15;
    int tid = threadIdx.x;
    int tx = tid & 31, ty = tid >> 5;
#pragma unroll
    for (int i = 0; i < 4; ++i)
        tile[ty + i * 8][tx] = v[((size_t)b * Tk + t0 + ty + i * 8) * S + h * 64 + d0 + tx];
    __syncthreads();
#pragma unroll
    for (int i = 0; i < 4; ++i)
        vT[((size_t)bh * 64 + d0 + ty + i * 8) * Tk + t0 + tx] = tile[tx][ty + i * 8];
}

// ---------------- swapped-QK^T 32x32 attention tile: one wave = 32 q rows.
__device__ __forceinline__ void attn32(const u16* __restrict__ qh, const u16* __restrict__ kh,
                                       const u16* __restrict__ vh, u16* __restrict__ oh,
                                       int q0, int nkb, int Tk, int causal, int lq, int hi,
                                       int QS, int KS) {
    const u16* qb = qh + (size_t)(q0 + lq) * QS;
    s16x8 qf[4];
#pragma unroll
    for (int c = 0; c < 4; ++c) qf[c] = *(const s16x8*)&qb[c * 16 + hi * 8];

    f32x16 o0 = {}, o1 = {};
    float mr = -1e30f, lr = 0.f;

    for (int kb = 0; kb < nkb; ++kb) {
        const int ks = kb * 32;
        f32x16 s = {};
        const u16* kp = kh + (size_t)(ks + lq) * KS + hi * 8;
#pragma unroll
        for (int c = 0; c < 4; ++c) {
            s16x8 kf = *(const s16x8*)&kp[c * 16];
            s = MFMA32(kf, qf[c], s);
        }
        if (causal && kb == nkb - 1) {
#pragma unroll
            for (int r = 0; r < 16; ++r) {
                int kl = (r & 3) + 8 * (r >> 2) + 4 * hi;
                if (kl > lq) s[r] = -1e30f;
            }
        }
        float bm = fmaxf(fmaxf(fmaxf(s[0], s[1]), fmaxf(s[2], s[3])),
                         fmaxf(fmaxf(s[4], s[5]), fmaxf(s[6], s[7])));
        float bm2 = fmaxf(fmaxf(fmaxf(s[8], s[9]), fmaxf(s[10], s[11])),
                          fmaxf(fmaxf(s[12], s[13]), fmaxf(s[14], s[15])));
        bm = fmaxf(bm, bm2);
        bm = fmaxf(bm, __shfl_xor(bm, 32));
        float mn = fmaxf(mr, bm);
        float sc = __expf(mr - mn);
        mr = mn;
        float p[16];
        float rs = 0.f;
#pragma unroll
        for (int r = 0; r < 16; ++r) { p[r] = __expf(s[r] - mn); rs += p[r]; }
        rs += __shfl_xor(rs, 32);
        lr = lr * sc + rs;
#pragma unroll
        for (int r = 0; r < 16; ++r) { o0[r] *= sc; o1[r] *= sc; }

        u32 pk[8];
#pragma unroll
        for (int i = 0; i < 8; ++i)
            pk[i] = (u32)f2bf(p[2 * i]) | ((u32)f2bf(p[2 * i + 1]) << 16);
        u32 e1 = __shfl_xor(hi ? pk[0] : pk[2], 32);
        u32 e2 = __shfl_xor(hi ? pk[1] : pk[3], 32);
        u32 e3 = __shfl_xor(hi ? pk[4] : pk[6], 32);
        u32 e4 = __shfl_xor(hi ? pk[5] : pk[7], 32);
        union { s16x8 v; u32 w[4]; } pf0, pf1;
        pf0.w[0] = hi ? e1 : pk[0];
        pf0.w[1] = hi ? e2 : pk[1];
        pf0.w[2] = hi ? pk[2] : e1;
        pf0.w[3] = hi ? pk[3] : e2;
        pf1.w[0] = hi ? e3 : pk[4];
        pf1.w[1] = hi ? e4 : pk[5];
        pf1.w[2] = hi ? pk[6] : e3;
        pf1.w[3] = hi ? pk[7] : e4;

        const u16* v0 = vh + (size_t)lq * Tk + ks + hi * 8;
        const u16* v1 = vh + (size_t)(32 + lq) * Tk + ks + hi * 8;
        o0 = MFMA32(*(const s16x8*)&v0[0],  pf0.v, o0);
        o0 = MFMA32(*(const s16x8*)&v0[16], pf1.v, o0);
        o1 = MFMA32(*(const s16x8*)&v1[0],  pf0.v, o1);
        o1 = MFMA32(*(const s16x8*)&v1[16], pf1.v, o1);
    }

    float inv = 1.f / lr;
    u16* ob = oh + (size_t)(q0 + lq) * D_;
#pragma unroll
    for (int r = 0; r < 16; ++r) {
        int hd = (r & 3) + 8 * (r >> 2) + 4 * hi;
        ob[hd] = f2bf(o0[r] * inv);
        ob[hd + 32] = f2bf(o1[r] * inv);
    }
}

// ---------------- causal self-attention: paired 32-row q-tiles, uniform iters/wave
__global__ __launch_bounds__(256) void attn_causal32(const u16* __restrict__ q, const u16* __restrict__ k,
                                                     const u16* __restrict__ vT, u16* __restrict__ o,
                                                     int Tq, int Tk, int QS, int KS) {
    const int lane = threadIdx.x & 63, wid = threadIdx.x >> 6;
    const int lq = lane & 31, hi = lane >> 5;
    const int ntile = Tq / 32;            // 64
    const int ppb = (ntile / 2) / 4;      // 8 pairs per block
    const int bh = blockIdx.x / ppb;
    const int p = (blockIdx.x % ppb) * 4 + wid;
    const int b = bh >> 4, h = bh & 15;

    const u16* qh = q + ((size_t)b * Tq) * QS + h * 64;
    const u16* kh = k + ((size_t)b * Tk) * KS + h * 64;
    const u16* vh = vT + ((size_t)bh * 64) * Tk;
    u16* oh = o + ((size_t)b * Tq) * D_ + h * 64;

    const int tA = p, tB = ntile - 1 - p;
    attn32(qh, kh, vh, oh, tA * 32, tA + 1, Tk, 1, lq, hi, QS, KS);
    attn32(qh, kh, vh, oh, tB * 32, tB + 1, Tk, 1, lq, hi, QS, KS);
}

// ---------------- non-causal cross-attention: one wave per 32-row q-tile
__global__ __launch_bounds__(256) void attn_plain32(const u16* __restrict__ q, const u16* __restrict__ k,
                                                    const u16* __restrict__ vT, u16* __restrict__ o,
                                                    int Tq, int Tk, int QS, int KS) {
    const int lane = threadIdx.x & 63, wid = threadIdx.x >> 6;
    const int lq = lane & 31, hi = lane >> 5;
    const int tpb = (Tq / 32) / 4;        // 16 tiles per block
    const int bh = blockIdx.x / tpb;
    const int qt = (blockIdx.x % tpb) * 4 + wid;
    const int b = bh >> 4, h = bh & 15;

    const u16* qh = q + ((size_t)b * Tq) * QS + h * 64;
    const u16* kh = k + ((size_t)b * Tk) * KS + h * 64;
    const u16* vh = vT + ((size_t)bh * 64) * Tk;
    u16* oh = o + ((size_t)b * Tq) * D_ + h * 64;

    attn32(qh, kh, vh, oh, qt * 32, Tk / 32, Tk, 0, lq, hi, QS, KS);
}

// ---------------- fused residual add + RMSNorm: one WAVE per row, 4x float4 per lane
__global__ __launch_bounds__(256) void addnorm(const float* __restrict__ xa, const float* __restrict__ xb,
                                               const float* __restrict__ gg, float* __restrict__ fo,
                                               u16* __restrict__ bo) {
    int row = blockIdx.x * 4 + (threadIdx.x >> 6);
    int lane = threadIdx.x & 63;
    const float4* pa = (const float4*)(xa + (size_t)row * D_);
    const float4* pb = (const float4*)(xb + (size_t)row * D_);
    float4 v[4];
    float ss = 0.f;
#pragma unroll
    for (int j = 0; j < 4; ++j) {
        float4 a = pa[lane + 64 * j];
        float4 b = pb[lane + 64 * j];
        v[j].x = a.x + b.x; v[j].y = a.y + b.y; v[j].z = a.z + b.z; v[j].w = a.w + b.w;
        ss += v[j].x * v[j].x + v[j].y * v[j].y + v[j].z * v[j].z + v[j].w * v[j].w;
    }
    ss += __shfl_xor(ss, 1);
    ss += __shfl_xor(ss, 2);
    ss += __shfl_xor(ss, 4);
    ss += __shfl_xor(ss, 8);
    ss += __shfl_xor(ss, 16);
    ss += __shfl_xor(ss, 32);
    float s = rsqrtf(ss * (1.0f / D_) + 1e-6f);
#pragma unroll
    for (int j = 0; j < 4; ++j) {
        float4 gv = ((const float4*)gg)[lane + 64 * j];
        float yx = v[j].x * s * gv.x, yy = v[j].y * s * gv.y;
        float yz = v[j].z * s * gv.z, yw = v[j].w * s * gv.w;
        if (fo) {
            float4 o4; o4.x = yx; o4.y = yy; o4.z = yz; o4.w = yw;
            ((float4*)(fo + (size_t)row * D_))[lane + 64 * j] = o4;
        }
        if (bo) {
            u64 pk = (u64)f2bf(yx) | ((u64)f2bf(yy) << 16) | ((u64)f2bf(yz) << 32) | ((u64)f2bf(yw) << 48);
            ((u64*)(bo + (size_t)row * D_))[lane + 64 * j] = pk;
        }
    }
}

extern "C" void kernel_launch(void* const* d_in, const int* in_sizes, int n_in,
                              void* d_out, int out_size, void* d_ws, size_t ws_size,
                              hipStream_t stream) {
    const float* x    = (const float*)d_in[0];
    const float* mem  = (const float*)d_in[1];
    const float* fr   = (const float*)d_in[2];
    const float* wsaq = (const float*)d_in[4];
    const float* wsak = (const float*)d_in[5];
    const float* wsav = (const float*)d_in[6];
    const float* wsao = (const float*)d_in[7];
    const float* wcaq = (const float*)d_in[8];
    const float* wcak = (const float*)d_in[9];
    const float* wcav = (const float*)d_in[10];
    const float* wcao = (const float*)d_in[11];
    const float* w1   = (const float*)d_in[12];
    const float* w3   = (const float*)d_in[13];
    const float* w2   = (const float*)d_in[14];
    const float* g_sa = (const float*)d_in[15];
    const float* g_ca = (const float*)d_in[16];
    const float* g_ff = (const float*)d_in[17];
    float* outF = (float*)d_out;

    char* p = (char*)d_ws;
    auto alloc = [&](size_t bytes) { char* r = p; p += (bytes + 255) & ~(size_t)255; return r; };
    const size_t DD2 = (size_t)1024 * 1024 * 2;
    u16* wqkvT = (u16*)alloc(3 * DD2);                 // [3072][1024] fused q|k|v
    u16* saoT  = (u16*)alloc(DD2);
    u16* caqT  = (u16*)alloc(DD2);
    u16* wkvT  = (u16*)alloc(2 * DD2);                 // [2048][1024] fused k|v (CA)
    u16* caoT  = (u16*)alloc(DD2);
    u16* w1T   = (u16*)alloc((size_t)HIDP_ * 1024 * 2);
    u16* w3T   = (u16*)alloc((size_t)HIDP_ * 1024 * 2);
    u16* w2T   = (u16*)alloc((size_t)1024 * HIDP_ * 2);
    u16* Ab    = (u16*)alloc((size_t)8192 * 1024 * 2);
    u16* memb  = (u16*)alloc((size_t)2048 * 1024 * 2);
    char* qkvRaw = alloc((size_t)8192 * 3072 * 2);     // SA fused q|k|v [8192][3072]
    u16* qkvb = (u16*)qkvRaw;
    u16* kvb  = (u16*)qkvRaw;                          // CA k|v [2048][2048] (aliased; used after SA)
    u16* caqb = (u16*)(qkvRaw + (size_t)25165824);     // CA q [8192][1024] (aliased upper region)
    u16* vtb  = (u16*)alloc((size_t)8192 * 1024 * 2);
    u16* ob   = (u16*)alloc((size_t)8192 * 1024 * 2);
    float* Pf = (float*)alloc((size_t)8192 * 1024 * 4);
    float* Rf = (float*)alloc((size_t)8192 * 1024 * 4);
    u16* Hb   = (u16*)alloc((size_t)8192 * HIDP_ * 2);

    dim3 blk(256);

    // weight prep (fused QKV rows: q 0-1023 | k 1024-2047 | v 2048-3071)
    wt_cast<<<dim3(32, 32), blk, 0, stream>>>(wsaq, wqkvT,               1024, 1024, 1024, 1024);
    wt_cast<<<dim3(32, 32), blk, 0, stream>>>(wsak, wqkvT + 1024 * 1024, 1024, 1024, 1024, 1024);
    wt_cast<<<dim3(32, 32), blk, 0, stream>>>(wsav, wqkvT + 2048 * 1024, 1024, 1024, 1024, 1024);
    wt_cast<<<dim3(32, 32), blk, 0, stream>>>(wsao, saoT, 1024, 1024, 1024, 1024);
    wt_cast<<<dim3(32, 32), blk, 0, stream>>>(wcaq, caqT, 1024, 1024, 1024, 1024);
    wt_cast<<<dim3(32, 32), blk, 0, stream>>>(wcak, wkvT,               1024, 1024, 1024, 1024);
    wt_cast<<<dim3(32, 32), blk, 0, stream>>>(wcav, wkvT + 1024 * 1024, 1024, 1024, 1024, 1024);
    wt_cast<<<dim3(32, 32), blk, 0, stream>>>(wcao, caoT, 1024, 1024, 1024, 1024);
    wt_cast<<<dim3(88, 32), blk, 0, stream>>>(w1, w1T, 1024, HID_, 1024, HIDP_);
    wt_cast<<<dim3(88, 32), blk, 0, stream>>>(w3, w3T, 1024, HID_, 1024, HIDP_);
    wt_cast<<<dim3(32, 88), blk, 0, stream>>>(w2, w2T, HID_, 1024, HIDP_, 1024);

    cast_bf16<<<8192, blk, 0, stream>>>(x, Ab, 2097152);
    cast_bf16<<<2048, blk, 0, stream>>>(mem, memb, 524288);

    // ---- self-attention (fused QKV projection via dual-panel: cols n and n+1536)
    gemm_dual<<<768, blk, 0, stream>>>(Ab, wqkvT, qkvb, nullptr, 8192, 3072, 1024, 1536, 1, 768);
    rope_qk<<<16384, blk, 0, stream>>>(qkvb, qkvb + 1024, fr, 3072);
    vtrans<<<dim3(64, 64, 2), blk, 0, stream>>>(qkvb + 2048, vtb, 2048, 3072);
    attn_causal32<<<512, blk, 0, stream>>>(qkvb, qkvb + 1024, vtb, ob, 2048, 2048, 3072, 3072);
    gemm_dual<<<256, blk, 0, stream>>>(ob, saoT, Pf, nullptr, 8192, 1024, 1024, 512, 0, 256);
    addnorm<<<2048, blk, 0, stream>>>(x, Pf, g_sa, Rf, Ab);

    // ---- cross-attention (fused KV projection; q scaled via mode 4)
    gemm_dual<<<256, blk, 0, stream>>>(Ab, caqT, caqb, nullptr, 8192, 1024, 1024, 512, 4, 256);
    gemm_bf16<<<256, blk, 0, stream>>>(memb, wkvT, kvb, nullptr, 2048, 2048, 1024, 1, 256);
    vtrans<<<dim3(64, 16, 2), blk, 0, stream>>>(kvb + 1024, vtb, 512, 2048);
    attn_plain32<<<1024, blk, 0, stream>>>(caqb, kvb, vtb, ob, 2048, 512, 1024, 2048);
    gemm_dual<<<256, blk, 0, stream>>>(ob, caoT, Pf, nullptr, 8192, 1024, 1024, 512, 0, 256);
    addnorm<<<2048, blk, 0, stream>>>(Rf, Pf, g_ca, Rf, Ab);

    // ---- FFN (SwiGLU): fused w1+w3 -> H, then dual down-proj
    gemm_w13<<<1408, blk, 0, stream>>>(Ab, w1T, w3T, Hb, 8192, HIDP_, 1024, 1408);
    gemm_dual<<<256, blk, 0, stream>>>(Hb, w2T, Pf, nullptr, 8192, 1024, HIDP_, 512, 0, 256);
    addnorm<<<2048, blk, 0, stream>>>(Rf, Pf, g_ff, outF, nullptr);
}

// Round 12
// 940.772 us; speedup vs baseline: 1.2001x; 1.2001x over previous
//
#include <hip/hip_runtime.h>
#include <hip/hip_bf16.h>

typedef __attribute__((ext_vector_type(8))) short s16x8;
typedef __attribute__((ext_vector_type(4))) float f32x4;
typedef __attribute__((ext_vector_type(16))) float f32x16;
typedef unsigned short u16;
typedef unsigned int u32;
typedef unsigned long long u64;

#define MFMA(a,b,c) __builtin_amdgcn_mfma_f32_16x16x32_bf16(a,b,c,0,0,0)
#define MFMA32(a,b,c) __builtin_amdgcn_mfma_f32_32x32x16_bf16(a,b,c,0,0,0)

constexpr int B_ = 4, T_ = 2048, TKV_ = 512, D_ = 1024, H_ = 16, HD_ = 64;
constexpr int HID_ = 2736, HIDP_ = 2816; // padded to 22*128

__device__ __forceinline__ float bf2f(u16 x) {
    union { float f; u32 u; } c; c.u = ((u32)x) << 16; return c.f;
}
__device__ __forceinline__ u16 f2bf(float f) {
    union { float f; u32 u; } c; c.f = f;
    u32 r = c.u + 0x7fffu + ((c.u >> 16) & 1u);
    return (u16)(r >> 16);
}

__device__ __forceinline__ void gload16(const void* g, void* l) {
    __builtin_amdgcn_global_load_lds(
        (const __attribute__((address_space(1))) u32*)g,
        (__attribute__((address_space(3))) u32*)l, 16, 0, 0);
}

// ---------------- weight transpose + cast:  W[K,N] f32 -> WT[Np,Kp] bf16 (zero-padded)
__global__ __launch_bounds__(256) void wt_cast(const float* __restrict__ W, u16* __restrict__ WT,
                                               int K, int N, int Kp, int Np) {
    __shared__ float t[32][33];
    int tid = threadIdx.x;
    int tx = tid & 31, ty = tid >> 5;
    int n0 = blockIdx.x * 32, k0 = blockIdx.y * 32;
#pragma unroll
    for (int i = 0; i < 4; ++i) {
        int kk = k0 + ty + i * 8, nn = n0 + tx;
        t[ty + i * 8][tx] = (kk < K && nn < N) ? W[(size_t)kk * N + nn] : 0.f;
    }
    __syncthreads();
#pragma unroll
    for (int i = 0; i < 4; ++i) {
        int nn = n0 + ty + i * 8, kk = k0 + tx;
        WT[(size_t)nn * Kp + kk] = f2bf(t[tx][ty + i * 8]);
    }
}

// ---------------- f32 -> bf16 cast (4 elems/thread)
__global__ __launch_bounds__(256) void cast_bf16(const float* __restrict__ in, u16* __restrict__ out, int n4) {
    int i = blockIdx.x * 256 + threadIdx.x;
    if (i >= n4) return;
    float4 v = ((const float4*)in)[i];
    u64 pk = (u64)f2bf(v.x) | ((u64)f2bf(v.y) << 16) | ((u64)f2bf(v.z) << 32) | ((u64)f2bf(v.w) << 48);
    ((u64*)out)[i] = pk;
}

// ---------------- epilogue store helper
__device__ __forceinline__ void gemm_store(void* C, const u16* mul, size_t idx, float v, int mode) {
    if (mode == 0) {
        ((float*)C)[idx] = v;
    } else if (mode == 1) {
        ((u16*)C)[idx] = f2bf(v);
    } else if (mode == 2) {
        float sg = 1.f / (1.f + __expf(-v));
        ((u16*)C)[idx] = f2bf(v * sg);
    } else if (mode == 3) {
        float h = bf2f(mul[idx]);
        ((u16*)C)[idx] = f2bf(v * h);
    } else {
        ((u16*)C)[idx] = f2bf(v * 0.125f);
    }
}

// LDS slot swizzle (T2, rule #21): physical 16B-slot p of row r holds logical
// slot p^(r&7); staged via inverse-permuted GLOBAL source (LDS dest linear for
// global_load_lds); reads apply the same XOR.

// ---------------- GEMM 128x128 tile, 4 waves, SINGLE-buffered (32 KiB LDS), slot-swizzled.
// (r3/r9 proven structure; inter-block overlap hides the stage drain)
__global__ __launch_bounds__(256) void gemm_bf16(const u16* __restrict__ A, const u16* __restrict__ Bt,
                                                 void* __restrict__ C, const u16* __restrict__ mul,
                                                 int M, int N, int K, int mode, int nwg) {
    __shared__ __align__(16) u16 As[128 * 64];
    __shared__ __align__(16) u16 Bs[128 * 64];
    const int tid = threadIdx.x;
    const int lane = tid & 63, wid = tid >> 6;
    const int wr = wid >> 1, wc = wid & 1;
    const int li = lane & 15, g = lane >> 4;

    int bid = (int)blockIdx.x;
    bid = (bid & 7) * (nwg >> 3) + (bid >> 3);

    const int tn = N >> 7;
    const int m0 = (bid / tn) * 128, n0 = (bid % tn) * 128;

    const int rowst = tid >> 3;
    const int colb = (((tid & 7) ^ ((tid >> 3) & 7)) * 16);   // inverse-swizzled source slot
    const char* ga = (const char*)A + ((size_t)(m0 + rowst) * K) * 2 + colb;
    const char* gb = (const char*)Bt + ((size_t)(n0 + rowst) * K) * 2 + colb;
    const size_t rstride = (size_t)32 * K * 2;

    f32x4 acc[4][4] = {};
    const int nt = K >> 6;

    for (int t = 0; t < nt; ++t) {
#pragma unroll
        for (int i = 0; i < 4; ++i) {
            gload16(ga + (size_t)t * 128 + i * rstride, (char*)As + i * 4096 + wid * 1024);
            gload16(gb + (size_t)t * 128 + i * rstride, (char*)Bs + i * 4096 + wid * 1024);
        }
        __syncthreads();
#pragma unroll
        for (int kk = 0; kk < 2; ++kk) {
            s16x8 aF[4], bF[4];
            const int sl = ((kk << 2) | g) ^ (li & 7);
#pragma unroll
            for (int m = 0; m < 4; ++m) aF[m] = *(const s16x8*)&As[(wr * 64 + m * 16 + li) * 64 + sl * 8];
#pragma unroll
            for (int n = 0; n < 4; ++n) bF[n] = *(const s16x8*)&Bs[(wc * 64 + n * 16 + li) * 64 + sl * 8];
#pragma unroll
            for (int m = 0; m < 4; ++m)
#pragma unroll
                for (int n = 0; n < 4; ++n)
                    acc[m][n] = MFMA(aF[m], bF[n], acc[m][n]);
        }
        __syncthreads();
    }

#pragma unroll
    for (int m = 0; m < 4; ++m)
#pragma unroll
        for (int n = 0; n < 4; ++n)
#pragma unroll
            for (int r = 0; r < 4; ++r) {
                size_t row = m0 + wr * 64 + m * 16 + g * 4 + r;
                size_t col = n0 + wc * 64 + n * 16 + li;
                gemm_store(C, mul, row * N + col, acc[m][n][r], mode);
            }
}

// ---------------- fused SwiGLU hidden GEMM: H = silu(A@W1t^T) * (A@W3t^T).
// v2 (this round): A staged in LDS (16 KiB, 4 gload_lds/thread); B1/B3 fragments
// read DIRECTLY global->register. Mechanism: barrier's vmcnt(0) drain covers only
// A's 4 loads (was 12); B register loads pipeline ACROSS barriers (waited at use,
// not at barrier). B rows are L2-hot (shared across 64 M-blocks).
__global__ __launch_bounds__(256) void gemm_w13(const u16* __restrict__ A, const u16* __restrict__ B1t,
                                                const u16* __restrict__ B3t, u16* __restrict__ Hout,
                                                int M, int N, int K, int nwg) {
    __shared__ __align__(16) u16 As[128 * 64];   // 16 KiB
    const int tid = threadIdx.x;
    const int lane = tid & 63, wid = tid >> 6;
    const int wr = wid >> 1, wc = wid & 1;
    const int li = lane & 15, g = lane >> 4;

    int bid = (int)blockIdx.x;
    bid = (bid & 7) * (nwg >> 3) + (bid >> 3);

    const int tn = N >> 7;
    const int m0 = (bid / tn) * 128, n0 = (bid % tn) * 128;

    const int rowst = tid >> 3;
    const int colb = (((tid & 7) ^ ((tid >> 3) & 7)) * 16);
    const char* ga = (const char*)A + ((size_t)(m0 + rowst) * K) * 2 + colb;
    const size_t rstride = (size_t)32 * K * 2;

    // direct-B row bases (u16 element pointers), rows n0 + wc*64 + n*16 + li
    const u16* gb1[4];
    const u16* gb3[4];
#pragma unroll
    for (int n = 0; n < 4; ++n) {
        size_t row = (size_t)(n0 + wc * 64 + n * 16 + li);
        gb1[n] = B1t + row * K + g * 8;
        gb3[n] = B3t + row * K + g * 8;
    }

    f32x4 acc1[4][4] = {}, acc3[4][4] = {};
    const int nt = K >> 6;

    for (int t = 0; t < nt; ++t) {
#pragma unroll
        for (int i = 0; i < 4; ++i)
            gload16(ga + (size_t)t * 128 + i * rstride, (char*)As + i * 4096 + wid * 1024);
        __syncthreads();
#pragma unroll
        for (int kk = 0; kk < 2; ++kk) {
            const int sl = ((kk << 2) | g) ^ (li & 7);
            const int kof = t * 64 + kk * 32;
            s16x8 aF[4], b1F[4], b3F[4];
#pragma unroll
            for (int n = 0; n < 4; ++n) b1F[n] = *(const s16x8*)&gb1[n][kof];
#pragma unroll
            for (int n = 0; n < 4; ++n) b3F[n] = *(const s16x8*)&gb3[n][kof];
#pragma unroll
            for (int m = 0; m < 4; ++m) aF[m] = *(const s16x8*)&As[(wr * 64 + m * 16 + li) * 64 + sl * 8];
#pragma unroll
            for (int m = 0; m < 4; ++m)
#pragma unroll
                for (int n = 0; n < 4; ++n)
                    acc1[m][n] = MFMA(aF[m], b1F[n], acc1[m][n]);
#pragma unroll
            for (int m = 0; m < 4; ++m)
#pragma unroll
                for (int n = 0; n < 4; ++n)
                    acc3[m][n] = MFMA(aF[m], b3F[n], acc3[m][n]);
        }
        __syncthreads();
    }

#pragma unroll
    for (int m = 0; m < 4; ++m)
#pragma unroll
        for (int n = 0; n < 4; ++n)
#pragma unroll
            for (int r = 0; r < 4; ++r) {
                size_t row = m0 + wr * 64 + m * 16 + g * 4 + r;
                size_t col = n0 + wc * 64 + n * 16 + li;
                float h1 = acc1[m][n][r];
                float h3 = acc3[m][n][r];
                float sg = 1.f / (1.f + __expf(-h1));
                Hout[row * N + col] = f2bf(h1 * sg * h3);
            }
}

// ---------------- RoPE in-place on q and k (strided); q additionally scaled by 0.125
__global__ __launch_bounds__(256) void rope_qk(u16* __restrict__ q, u16* __restrict__ k,
                                               const float* __restrict__ fr, int S) {
    size_t idx = (size_t)blockIdx.x * 256 + threadIdx.x; // over B*T*H*(HD/2)
    int i = (int)(idx & 31);
    int h = (int)((idx >> 5) & 15);
    size_t bt = idx >> 9;             // b*T + t
    int t = (int)(bt & (T_ - 1));
    float2 cs = ((const float2*)fr)[t * 32 + i];
    size_t off = bt * (size_t)S + h * 64 + 2 * i;
    {
        u32* p = (u32*)(q + off);
        u32 w = *p;
        float a = bf2f((u16)(w & 0xffff)), b = bf2f((u16)(w >> 16));
        *p = (u32)f2bf((a * cs.x - b * cs.y) * 0.125f) | ((u32)f2bf((a * cs.y + b * cs.x) * 0.125f) << 16);
    }
    {
        u32* p = (u32*)(k + off);
        u32 w = *p;
        float a = bf2f((u16)(w & 0xffff)), b = bf2f((u16)(w >> 16));
        *p = (u32)f2bf(a * cs.x - b * cs.y) | ((u32)f2bf(a * cs.y + b * cs.x) << 16);
    }
}

// ---------------- V transpose: v[B,Tk,*] (stride S) bf16 -> vT[B,H,HD,Tk] bf16
__global__ __launch_bounds__(256) void vtrans(const u16* __restrict__ v, u16* __restrict__ vT,
                                              int Tk, int S) {
    __shared__ u16 tile[32][34];
    int bh = blockIdx.x;
    int t0 = blockIdx.y * 32, d0 = blockIdx.z * 32;
    int b = bh >> 4, h = bh & 15;
    int tid = threadIdx.x;
    int tx = tid & 31, ty = tid >> 5;
#pragma unroll
    for (int i = 0; i < 4; ++i)
        tile[ty + i * 8][tx] = v[((size_t)b * Tk + t0 + ty + i * 8) * S + h * 64 + d0 + tx];
    __syncthreads();
#pragma unroll
    for (int i = 0; i < 4; ++i)
        vT[((size_t)bh * 64 + d0 + ty + i * 8) * Tk + t0 + tx] = tile[tx][ty + i * 8];
}

// ---------------- swapped-QK^T 32x32 attention tile: one wave = 32 q rows.
__device__ __forceinline__ void attn32(const u16* __restrict__ qh, const u16* __restrict__ kh,
                                       const u16* __restrict__ vh, u16* __restrict__ oh,
                                       int q0, int nkb, int Tk, int causal, int lq, int hi,
                                       int QS, int KS) {
    const u16* qb = qh + (size_t)(q0 + lq) * QS;
    s16x8 qf[4];
#pragma unroll
    for (int c = 0; c < 4; ++c) qf[c] = *(const s16x8*)&qb[c * 16 + hi * 8];

    f32x16 o0 = {}, o1 = {};
    float mr = -1e30f, lr = 0.f;

    for (int kb = 0; kb < nkb; ++kb) {
        const int ks = kb * 32;
        f32x16 s = {};
        const u16* kp = kh + (size_t)(ks + lq) * KS + hi * 8;
#pragma unroll
        for (int c = 0; c < 4; ++c) {
            s16x8 kf = *(const s16x8*)&kp[c * 16];
            s = MFMA32(kf, qf[c], s);
        }
        if (causal && kb == nkb - 1) {
#pragma unroll
            for (int r = 0; r < 16; ++r) {
                int kl = (r & 3) + 8 * (r >> 2) + 4 * hi;
                if (kl > lq) s[r] = -1e30f;
            }
        }
        float bm = fmaxf(fmaxf(fmaxf(s[0], s[1]), fmaxf(s[2], s[3])),
                         fmaxf(fmaxf(s[4], s[5]), fmaxf(s[6], s[7])));
        float bm2 = fmaxf(fmaxf(fmaxf(s[8], s[9]), fmaxf(s[10], s[11])),
                          fmaxf(fmaxf(s[12], s[13]), fmaxf(s[14], s[15])));
        bm = fmaxf(bm, bm2);
        bm = fmaxf(bm, __shfl_xor(bm, 32));
        float mn = fmaxf(mr, bm);
        float sc = __expf(mr - mn);
        mr = mn;
        float p[16];
        float rs = 0.f;
#pragma unroll
        for (int r = 0; r < 16; ++r) { p[r] = __expf(s[r] - mn); rs += p[r]; }
        rs += __shfl_xor(rs, 32);
        lr = lr * sc + rs;
#pragma unroll
        for (int r = 0; r < 16; ++r) { o0[r] *= sc; o1[r] *= sc; }

        u32 pk[8];
#pragma unroll
        for (int i = 0; i < 8; ++i)
            pk[i] = (u32)f2bf(p[2 * i]) | ((u32)f2bf(p[2 * i + 1]) << 16);
        u32 e1 = __shfl_xor(hi ? pk[0] : pk[2], 32);
        u32 e2 = __shfl_xor(hi ? pk[1] : pk[3], 32);
        u32 e3 = __shfl_xor(hi ? pk[4] : pk[6], 32);
        u32 e4 = __shfl_xor(hi ? pk[5] : pk[7], 32);
        union { s16x8 v; u32 w[4]; } pf0, pf1;
        pf0.w[0] = hi ? e1 : pk[0];
        pf0.w[1] = hi ? e2 : pk[1];
        pf0.w[2] = hi ? pk[2] : e1;
        pf0.w[3] = hi ? pk[3] : e2;
        pf1.w[0] = hi ? e3 : pk[4];
        pf1.w[1] = hi ? e4 : pk[5];
        pf1.w[2] = hi ? pk[6] : e3;
        pf1.w[3] = hi ? pk[7] : e4;

        const u16* v0 = vh + (size_t)lq * Tk + ks + hi * 8;
        const u16* v1 = vh + (size_t)(32 + lq) * Tk + ks + hi * 8;
        o0 = MFMA32(*(const s16x8*)&v0[0],  pf0.v, o0);
        o0 = MFMA32(*(const s16x8*)&v0[16], pf1.v, o0);
        o1 = MFMA32(*(const s16x8*)&v1[0],  pf0.v, o1);
        o1 = MFMA32(*(const s16x8*)&v1[16], pf1.v, o1);
    }

    float inv = 1.f / lr;
    u16* ob = oh + (size_t)(q0 + lq) * D_;
#pragma unroll
    for (int r = 0; r < 16; ++r) {
        int hd = (r & 3) + 8 * (r >> 2) + 4 * hi;
        ob[hd] = f2bf(o0[r] * inv);
        ob[hd + 32] = f2bf(o1[r] * inv);
    }
}

// ---------------- causal self-attention: paired 32-row q-tiles, uniform iters/wave
__global__ __launch_bounds__(256) void attn_causal32(const u16* __restrict__ q, const u16* __restrict__ k,
                                                     const u16* __restrict__ vT, u16* __restrict__ o,
                                                     int Tq, int Tk, int QS, int KS) {
    const int lane = threadIdx.x & 63, wid = threadIdx.x >> 6;
    const int lq = lane & 31, hi = lane >> 5;
    const int ntile = Tq / 32;            // 64
    const int ppb = (ntile / 2) / 4;      // 8 pairs per block
    const int bh = blockIdx.x / ppb;
    const int p = (blockIdx.x % ppb) * 4 + wid;
    const int b = bh >> 4, h = bh & 15;

    const u16* qh = q + ((size_t)b * Tq) * QS + h * 64;
    const u16* kh = k + ((size_t)b * Tk) * KS + h * 64;
    const u16* vh = vT + ((size_t)bh * 64) * Tk;
    u16* oh = o + ((size_t)b * Tq) * D_ + h * 64;

    const int tA = p, tB = ntile - 1 - p;
    attn32(qh, kh, vh, oh, tA * 32, tA + 1, Tk, 1, lq, hi, QS, KS);
    attn32(qh, kh, vh, oh, tB * 32, tB + 1, Tk, 1, lq, hi, QS, KS);
}

// ---------------- non-causal cross-attention: one wave per 32-row q-tile
__global__ __launch_bounds__(256) void attn_plain32(const u16* __restrict__ q, const u16* __restrict__ k,
                                                    const u16* __restrict__ vT, u16* __restrict__ o,
                                                    int Tq, int Tk, int QS, int KS) {
    const int lane = threadIdx.x & 63, wid = threadIdx.x >> 6;
    const int lq = lane & 31, hi = lane >> 5;
    const int tpb = (Tq / 32) / 4;        // 16 tiles per block
    const int bh = blockIdx.x / tpb;
    const int qt = (blockIdx.x % tpb) * 4 + wid;
    const int b = bh >> 4, h = bh & 15;

    const u16* qh = q + ((size_t)b * Tq) * QS + h * 64;
    const u16* kh = k + ((size_t)b * Tk) * KS + h * 64;
    const u16* vh = vT + ((size_t)bh * 64) * Tk;
    u16* oh = o + ((size_t)b * Tq) * D_ + h * 64;

    attn32(qh, kh, vh, oh, qt * 32, Tk / 32, Tk, 0, lq, hi, QS, KS);
}

// ---------------- fused residual add + RMSNorm: one WAVE per row, 4x float4 per lane
__global__ __launch_bounds__(256) void addnorm(const float* __restrict__ xa, const float* __restrict__ xb,
                                               const float* __restrict__ gg, float* __restrict__ fo,
                                               u16* __restrict__ bo) {
    int row = blockIdx.x * 4 + (threadIdx.x >> 6);
    int lane = threadIdx.x & 63;
    const float4* pa = (const float4*)(xa + (size_t)row * D_);
    const float4* pb = (const float4*)(xb + (size_t)row * D_);
    float4 v[4];
    float ss = 0.f;
#pragma unroll
    for (int j = 0; j < 4; ++j) {
        float4 a = pa[lane + 64 * j];
        float4 b = pb[lane + 64 * j];
        v[j].x = a.x + b.x; v[j].y = a.y + b.y; v[j].z = a.z + b.z; v[j].w = a.w + b.w;
        ss += v[j].x * v[j].x + v[j].y * v[j].y + v[j].z * v[j].z + v[j].w * v[j].w;
    }
    ss += __shfl_xor(ss, 1);
    ss += __shfl_xor(ss, 2);
    ss += __shfl_xor(ss, 4);
    ss += __shfl_xor(ss, 8);
    ss += __shfl_xor(ss, 16);
    ss += __shfl_xor(ss, 32);
    float s = rsqrtf(ss * (1.0f / D_) + 1e-6f);
#pragma unroll
    for (int j = 0; j < 4; ++j) {
        float4 gv = ((const float4*)gg)[lane + 64 * j];
        float yx = v[j].x * s * gv.x, yy = v[j].y * s * gv.y;
        float yz = v[j].z * s * gv.z, yw = v[j].w * s * gv.w;
        if (fo) {
            float4 o4; o4.x = yx; o4.y = yy; o4.z = yz; o4.w = yw;
            ((float4*)(fo + (size_t)row * D_))[lane + 64 * j] = o4;
        }
        if (bo) {
            u64 pk = (u64)f2bf(yx) | ((u64)f2bf(yy) << 16) | ((u64)f2bf(yz) << 32) | ((u64)f2bf(yw) << 48);
            ((u64*)(bo + (size_t)row * D_))[lane + 64 * j] = pk;
        }
    }
}

extern "C" void kernel_launch(void* const* d_in, const int* in_sizes, int n_in,
                              void* d_out, int out_size, void* d_ws, size_t ws_size,
                              hipStream_t stream) {
    const float* x    = (const float*)d_in[0];
    const float* mem  = (const float*)d_in[1];
    const float* fr   = (const float*)d_in[2];
    const float* wsaq = (const float*)d_in[4];
    const float* wsak = (const float*)d_in[5];
    const float* wsav = (const float*)d_in[6];
    const float* wsao = (const float*)d_in[7];
    const float* wcaq = (const float*)d_in[8];
    const float* wcak = (const float*)d_in[9];
    const float* wcav = (const float*)d_in[10];
    const float* wcao = (const float*)d_in[11];
    const float* w1   = (const float*)d_in[12];
    const float* w3   = (const float*)d_in[13];
    const float* w2   = (const float*)d_in[14];
    const float* g_sa = (const float*)d_in[15];
    const float* g_ca = (const float*)d_in[16];
    const float* g_ff = (const float*)d_in[17];
    float* outF = (float*)d_out;

    char* p = (char*)d_ws;
    auto alloc = [&](size_t bytes) { char* r = p; p += (bytes + 255) & ~(size_t)255; return r; };
    const size_t DD2 = (size_t)1024 * 1024 * 2;
    u16* wqkvT = (u16*)alloc(3 * DD2);                 // [3072][1024] fused q|k|v
    u16* saoT  = (u16*)alloc(DD2);
    u16* caqT  = (u16*)alloc(DD2);
    u16* wkvT  = (u16*)alloc(2 * DD2);                 // [2048][1024] fused k|v (CA)
    u16* caoT  = (u16*)alloc(DD2);
    u16* w1T   = (u16*)alloc((size_t)HIDP_ * 1024 * 2);
    u16* w3T   = (u16*)alloc((size_t)HIDP_ * 1024 * 2);
    u16* w2T   = (u16*)alloc((size_t)1024 * HIDP_ * 2);
    u16* Ab    = (u16*)alloc((size_t)8192 * 1024 * 2);
    u16* memb  = (u16*)alloc((size_t)2048 * 1024 * 2);
    char* qkvRaw = alloc((size_t)8192 * 3072 * 2);     // SA fused q|k|v [8192][3072]
    u16* qkvb = (u16*)qkvRaw;
    u16* kvb  = (u16*)qkvRaw;                          // CA k|v [2048][2048] (aliased; used after SA)
    u16* caqb = (u16*)(qkvRaw + (size_t)25165824);     // CA q [8192][1024] (aliased upper region)
    u16* vtb  = (u16*)alloc((size_t)8192 * 1024 * 2);
    u16* ob   = (u16*)alloc((size_t)8192 * 1024 * 2);
    float* Pf = (float*)alloc((size_t)8192 * 1024 * 4);
    float* Rf = (float*)alloc((size_t)8192 * 1024 * 4);
    u16* Hb   = (u16*)alloc((size_t)8192 * HIDP_ * 2);

    dim3 blk(256);

    // weight prep (fused QKV rows: q 0-1023 | k 1024-2047 | v 2048-3071)
    wt_cast<<<dim3(32, 32), blk, 0, stream>>>(wsaq, wqkvT,               1024, 1024, 1024, 1024);
    wt_cast<<<dim3(32, 32), blk, 0, stream>>>(wsak, wqkvT + 1024 * 1024, 1024, 1024, 1024, 1024);
    wt_cast<<<dim3(32, 32), blk, 0, stream>>>(wsav, wqkvT + 2048 * 1024, 1024, 1024, 1024, 1024);
    wt_cast<<<dim3(32, 32), blk, 0, stream>>>(wsao, saoT, 1024, 1024, 1024, 1024);
    wt_cast<<<dim3(32, 32), blk, 0, stream>>>(wcaq, caqT, 1024, 1024, 1024, 1024);
    wt_cast<<<dim3(32, 32), blk, 0, stream>>>(wcak, wkvT,               1024, 1024, 1024, 1024);
    wt_cast<<<dim3(32, 32), blk, 0, stream>>>(wcav, wkvT + 1024 * 1024, 1024, 1024, 1024, 1024);
    wt_cast<<<dim3(32, 32), blk, 0, stream>>>(wcao, caoT, 1024, 1024, 1024, 1024);
    wt_cast<<<dim3(88, 32), blk, 0, stream>>>(w1, w1T, 1024, HID_, 1024, HIDP_);
    wt_cast<<<dim3(88, 32), blk, 0, stream>>>(w3, w3T, 1024, HID_, 1024, HIDP_);
    wt_cast<<<dim3(32, 88), blk, 0, stream>>>(w2, w2T, HID_, 1024, HIDP_, 1024);

    cast_bf16<<<8192, blk, 0, stream>>>(x, Ab, 2097152);
    cast_bf16<<<2048, blk, 0, stream>>>(mem, memb, 524288);

    // ---- self-attention (fused QKV projection, N=3072)
    gemm_bf16<<<1536, blk, 0, stream>>>(Ab, wqkvT, qkvb, nullptr, 8192, 3072, 1024, 1, 1536);
    rope_qk<<<16384, blk, 0, stream>>>(qkvb, qkvb + 1024, fr, 3072);
    vtrans<<<dim3(64, 64, 2), blk, 0, stream>>>(qkvb + 2048, vtb, 2048, 3072);
    attn_causal32<<<512, blk, 0, stream>>>(qkvb, qkvb + 1024, vtb, ob, 2048, 2048, 3072, 3072);
    gemm_bf16<<<512, blk, 0, stream>>>(ob, saoT, Pf, nullptr, 8192, 1024, 1024, 0, 512);
    addnorm<<<2048, blk, 0, stream>>>(x, Pf, g_sa, Rf, Ab);

    // ---- cross-attention (fused KV projection, N=2048; q scaled via mode 4)
    gemm_bf16<<<512, blk, 0, stream>>>(Ab, caqT, caqb, nullptr, 8192, 1024, 1024, 4, 512);
    gemm_bf16<<<256, blk, 0, stream>>>(memb, wkvT, kvb, nullptr, 2048, 2048, 1024, 1, 256);
    vtrans<<<dim3(64, 16, 2), blk, 0, stream>>>(kvb + 1024, vtb, 512, 2048);
    attn_plain32<<<1024, blk, 0, stream>>>(caqb, kvb, vtb, ob, 2048, 512, 1024, 2048);
    gemm_bf16<<<512, blk, 0, stream>>>(ob, caoT, Pf, nullptr, 8192, 1024, 1024, 0, 512);
    addnorm<<<2048, blk, 0, stream>>>(Rf, Pf, g_ca, Rf, Ab);

    // ---- FFN (SwiGLU): fused w1+w3 -> H (direct-B v2), then down-proj
    gemm_w13<<<1408, blk, 0, stream>>>(Ab, w1T, w3T, Hb, 8192, HIDP_, 1024, 1408);
    gemm_bf16<<<512, blk, 0, stream>>>(Hb, w2T, Pf, nullptr, 8192, 1024, HIDP_, 0, 512);
    addnorm<<<2048, blk, 0, stream>>>(Rf, Pf, g_ff, outF, nullptr);
}

// Round 13
// 857.856 us; speedup vs baseline: 1.3161x; 1.0967x over previous
//
#include <hip/hip_runtime.h>
#include <hip/hip_bf16.h>

typedef __attribute__((ext_vector_type(8))) short s16x8;
typedef __attribute__((ext_vector_type(4))) float f32x4;
typedef __attribute__((ext_vector_type(16))) float f32x16;
typedef unsigned short u16;
typedef unsigned int u32;
typedef unsigned long long u64;

#define MFMA(a,b,c) __builtin_amdgcn_mfma_f32_16x16x32_bf16(a,b,c,0,0,0)
#define MFMA32(a,b,c) __builtin_amdgcn_mfma_f32_32x32x16_bf16(a,b,c,0,0,0)

constexpr int B_ = 4, T_ = 2048, TKV_ = 512, D_ = 1024, H_ = 16, HD_ = 64;
constexpr int HID_ = 2736, HIDP_ = 2816; // padded to 22*128

__device__ __forceinline__ float bf2f(u16 x) {
    union { float f; u32 u; } c; c.u = ((u32)x) << 16; return c.f;
}
__device__ __forceinline__ u16 f2bf(float f) {
    union { float f; u32 u; } c; c.f = f;
    u32 r = c.u + 0x7fffu + ((c.u >> 16) & 1u);
    return (u16)(r >> 16);
}

__device__ __forceinline__ void gload16(const void* g, void* l) {
    __builtin_amdgcn_global_load_lds(
        (const __attribute__((address_space(1))) u32*)g,
        (__attribute__((address_space(3))) u32*)l, 16, 0, 0);
}

// ---------------- weight transpose + cast:  W[K,N] f32 -> WT[Np,Kp] bf16 (zero-padded)
__global__ __launch_bounds__(256) void wt_cast(const float* __restrict__ W, u16* __restrict__ WT,
                                               int K, int N, int Kp, int Np) {
    __shared__ float t[32][33];
    int tid = threadIdx.x;
    int tx = tid & 31, ty = tid >> 5;
    int n0 = blockIdx.x * 32, k0 = blockIdx.y * 32;
#pragma unroll
    for (int i = 0; i < 4; ++i) {
        int kk = k0 + ty + i * 8, nn = n0 + tx;
        t[ty + i * 8][tx] = (kk < K && nn < N) ? W[(size_t)kk * N + nn] : 0.f;
    }
    __syncthreads();
#pragma unroll
    for (int i = 0; i < 4; ++i) {
        int nn = n0 + ty + i * 8, kk = k0 + tx;
        WT[(size_t)nn * Kp + kk] = f2bf(t[tx][ty + i * 8]);
    }
}

// ---------------- f32 -> bf16 cast (4 elems/thread)
__global__ __launch_bounds__(256) void cast_bf16(const float* __restrict__ in, u16* __restrict__ out, int n4) {
    int i = blockIdx.x * 256 + threadIdx.x;
    if (i >= n4) return;
    float4 v = ((const float4*)in)[i];
    u64 pk = (u64)f2bf(v.x) | ((u64)f2bf(v.y) << 16) | ((u64)f2bf(v.z) << 32) | ((u64)f2bf(v.w) << 48);
    ((u64*)out)[i] = pk;
}

// ---------------- epilogue store helper
__device__ __forceinline__ void gemm_store(void* C, const u16* mul, size_t idx, float v, int mode) {
    if (mode == 0) {
        ((float*)C)[idx] = v;
    } else if (mode == 1) {
        ((u16*)C)[idx] = f2bf(v);
    } else if (mode == 2) {
        float sg = 1.f / (1.f + __expf(-v));
        ((u16*)C)[idx] = f2bf(v * sg);
    } else if (mode == 3) {
        float h = bf2f(mul[idx]);
        ((u16*)C)[idx] = f2bf(v * h);
    } else {
        ((u16*)C)[idx] = f2bf(v * 0.125f);
    }
}

// LDS slot swizzle (T2, rule #21): physical 16B-slot p of row r holds logical
// slot p^(r&7); staged via inverse-permuted GLOBAL source (LDS dest linear for
// global_load_lds); reads apply the same XOR.
//
// Tile decode is N-MAJOR (m = bid % tm): each XCD's contiguous bid window spans
// many m-tiles but few n-tiles -> B panels stay L2-resident per XCD; A streams
// via L3 (16 MB << 256 MB). Cuts the 271 MB B re-fetch seen in r9-12.

// ---------------- GEMM 128x128 tile, 4 waves, SINGLE-buffered (32 KiB LDS), slot-swizzled.
__global__ __launch_bounds__(256) void gemm_bf16(const u16* __restrict__ A, const u16* __restrict__ Bt,
                                                 void* __restrict__ C, const u16* __restrict__ mul,
                                                 int M, int N, int K, int mode, int nwg) {
    __shared__ __align__(16) u16 As[128 * 64];
    __shared__ __align__(16) u16 Bs[128 * 64];
    const int tid = threadIdx.x;
    const int lane = tid & 63, wid = tid >> 6;
    const int wr = wid >> 1, wc = wid & 1;
    const int li = lane & 15, g = lane >> 4;

    int bid = (int)blockIdx.x;
    bid = (bid & 7) * (nwg >> 3) + (bid >> 3);

    const int tm = M >> 7;
    const int m0 = (bid % tm) * 128, n0 = (bid / tm) * 128;   // n-major decode

    const int rowst = tid >> 3;
    const int colb = (((tid & 7) ^ ((tid >> 3) & 7)) * 16);   // inverse-swizzled source slot
    const char* ga = (const char*)A + ((size_t)(m0 + rowst) * K) * 2 + colb;
    const char* gb = (const char*)Bt + ((size_t)(n0 + rowst) * K) * 2 + colb;
    const size_t rstride = (size_t)32 * K * 2;

    f32x4 acc[4][4] = {};
    const int nt = K >> 6;

    for (int t = 0; t < nt; ++t) {
#pragma unroll
        for (int i = 0; i < 4; ++i) {
            gload16(ga + (size_t)t * 128 + i * rstride, (char*)As + i * 4096 + wid * 1024);
            gload16(gb + (size_t)t * 128 + i * rstride, (char*)Bs + i * 4096 + wid * 1024);
        }
        __syncthreads();
#pragma unroll
        for (int kk = 0; kk < 2; ++kk) {
            s16x8 aF[4], bF[4];
            const int sl = ((kk << 2) | g) ^ (li & 7);
#pragma unroll
            for (int m = 0; m < 4; ++m) aF[m] = *(const s16x8*)&As[(wr * 64 + m * 16 + li) * 64 + sl * 8];
#pragma unroll
            for (int n = 0; n < 4; ++n) bF[n] = *(const s16x8*)&Bs[(wc * 64 + n * 16 + li) * 64 + sl * 8];
#pragma unroll
            for (int m = 0; m < 4; ++m)
#pragma unroll
                for (int n = 0; n < 4; ++n)
                    acc[m][n] = MFMA(aF[m], bF[n], acc[m][n]);
        }
        __syncthreads();
    }

#pragma unroll
    for (int m = 0; m < 4; ++m)
#pragma unroll
        for (int n = 0; n < 4; ++n)
#pragma unroll
            for (int r = 0; r < 4; ++r) {
                size_t row = m0 + wr * 64 + m * 16 + g * 4 + r;
                size_t col = n0 + wc * 64 + n * 16 + li;
                gemm_store(C, mul, row * N + col, acc[m][n][r], mode);
            }
}

// ---------------- fused SwiGLU hidden GEMM: H = silu(A@W1t^T) * (A@W3t^T).
// r9 version (425 TF): A,B1,B3 all LDS-staged (48 KiB), 12 loads/thread/K-tile.
__global__ __launch_bounds__(256) void gemm_w13(const u16* __restrict__ A, const u16* __restrict__ B1t,
                                                const u16* __restrict__ B3t, u16* __restrict__ Hout,
                                                int M, int N, int K, int nwg) {
    __shared__ __align__(16) u16 As[128 * 64];
    __shared__ __align__(16) u16 B1s[128 * 64];
    __shared__ __align__(16) u16 B3s[128 * 64];
    const int tid = threadIdx.x;
    const int lane = tid & 63, wid = tid >> 6;
    const int wr = wid >> 1, wc = wid & 1;
    const int li = lane & 15, g = lane >> 4;

    int bid = (int)blockIdx.x;
    bid = (bid & 7) * (nwg >> 3) + (bid >> 3);

    const int tm = M >> 7;
    const int m0 = (bid % tm) * 128, n0 = (bid / tm) * 128;   // n-major decode

    const int rowst = tid >> 3;
    const int colb = (((tid & 7) ^ ((tid >> 3) & 7)) * 16);
    const char* ga = (const char*)A + ((size_t)(m0 + rowst) * K) * 2 + colb;
    const char* gb1 = (const char*)B1t + ((size_t)(n0 + rowst) * K) * 2 + colb;
    const char* gb3 = (const char*)B3t + ((size_t)(n0 + rowst) * K) * 2 + colb;
    const size_t rstride = (size_t)32 * K * 2;

    f32x4 acc1[4][4] = {}, acc3[4][4] = {};
    const int nt = K >> 6;

    for (int t = 0; t < nt; ++t) {
#pragma unroll
        for (int i = 0; i < 4; ++i) {
            gload16(ga + (size_t)t * 128 + i * rstride, (char*)As + i * 4096 + wid * 1024);
            gload16(gb1 + (size_t)t * 128 + i * rstride, (char*)B1s + i * 4096 + wid * 1024);
            gload16(gb3 + (size_t)t * 128 + i * rstride, (char*)B3s + i * 4096 + wid * 1024);
        }
        __syncthreads();
#pragma unroll
        for (int kk = 0; kk < 2; ++kk) {
            const int sl = ((kk << 2) | g) ^ (li & 7);
            s16x8 aF[4];
#pragma unroll
            for (int m = 0; m < 4; ++m) aF[m] = *(const s16x8*)&As[(wr * 64 + m * 16 + li) * 64 + sl * 8];
            {   // W1 product
                s16x8 bF[4];
#pragma unroll
                for (int n = 0; n < 4; ++n) bF[n] = *(const s16x8*)&B1s[(wc * 64 + n * 16 + li) * 64 + sl * 8];
#pragma unroll
                for (int m = 0; m < 4; ++m)
#pragma unroll
                    for (int n = 0; n < 4; ++n)
                        acc1[m][n] = MFMA(aF[m], bF[n], acc1[m][n]);
            }
            {   // W3 product
                s16x8 bF[4];
#pragma unroll
                for (int n = 0; n < 4; ++n) bF[n] = *(const s16x8*)&B3s[(wc * 64 + n * 16 + li) * 64 + sl * 8];
#pragma unroll
                for (int m = 0; m < 4; ++m)
#pragma unroll
                    for (int n = 0; n < 4; ++n)
                        acc3[m][n] = MFMA(aF[m], bF[n], acc3[m][n]);
            }
        }
        __syncthreads();
    }

#pragma unroll
    for (int m = 0; m < 4; ++m)
#pragma unroll
        for (int n = 0; n < 4; ++n)
#pragma unroll
            for (int r = 0; r < 4; ++r) {
                size_t row = m0 + wr * 64 + m * 16 + g * 4 + r;
                size_t col = n0 + wc * 64 + n * 16 + li;
                float h1 = acc1[m][n][r];
                float h3 = acc3[m][n][r];
                float sg = 1.f / (1.f + __expf(-h1));
                Hout[row * N + col] = f2bf(h1 * sg * h3);
            }
}

// ---------------- RoPE in-place on q and k (strided); q additionally scaled by 0.125
__global__ __launch_bounds__(256) void rope_qk(u16* __restrict__ q, u16* __restrict__ k,
                                               const float* __restrict__ fr, int S) {
    size_t idx = (size_t)blockIdx.x * 256 + threadIdx.x; // over B*T*H*(HD/2)
    int i = (int)(idx & 31);
    int h = (int)((idx >> 5) & 15);
    size_t bt = idx >> 9;             // b*T + t
    int t = (int)(bt & (T_ - 1));
    float2 cs = ((const float2*)fr)[t * 32 + i];
    size_t off = bt * (size_t)S + h * 64 + 2 * i;
    {
        u32* p = (u32*)(q + off);
        u32 w = *p;
        float a = bf2f((u16)(w & 0xffff)), b = bf2f((u16)(w >> 16));
        *p = (u32)f2bf((a * cs.x - b * cs.y) * 0.125f) | ((u32)f2bf((a * cs.y + b * cs.x) * 0.125f) << 16);
    }
    {
        u32* p = (u32*)(k + off);
        u32 w = *p;
        float a = bf2f((u16)(w & 0xffff)), b = bf2f((u16)(w >> 16));
        *p = (u32)f2bf(a * cs.x - b * cs.y) | ((u32)f2bf(a * cs.y + b * cs.x) << 16);
    }
}

// ---------------- V transpose: v[B,Tk,*] (stride S) bf16 -> vT[B,H,HD,Tk] bf16
__global__ __launch_bounds__(256) void vtrans(const u16* __restrict__ v, u16* __restrict__ vT,
                                              int Tk, int S) {
    __shared__ u16 tile[32][34];
    int bh = blockIdx.x;
    int t0 = blockIdx.y * 32, d0 = blockIdx.z * 32;
    int b = bh >> 4, h = bh & 15;
    int tid = threadIdx.x;
    int tx = tid & 31, ty = tid >> 5;
#pragma unroll
    for (int i = 0; i < 4; ++i)
        tile[ty + i * 8][tx] = v[((size_t)b * Tk + t0 + ty + i * 8) * S + h * 64 + d0 + tx];
    __syncthreads();
#pragma unroll
    for (int i = 0; i < 4; ++i)
        vT[((size_t)bh * 64 + d0 + ty + i * 8) * Tk + t0 + tx] = tile[tx][ty + i * 8];
}

// ---------------- swapped-QK^T 32x32 attention tile: one wave = 32 q rows.
__device__ __forceinline__ void attn32(const u16* __restrict__ qh, const u16* __restrict__ kh,
                                       const u16* __restrict__ vh, u16* __restrict__ oh,
                                       int q0, int nkb, int Tk, int causal, int lq, int hi,
                                       int QS, int KS) {
    const u16* qb = qh + (size_t)(q0 + lq) * QS;
    s16x8 qf[4];
#pragma unroll
    for (int c = 0; c < 4; ++c) qf[c] = *(const s16x8*)&qb[c * 16 + hi * 8];

    f32x16 o0 = {}, o1 = {};
    float mr = -1e30f, lr = 0.f;

    for (int kb = 0; kb < nkb; ++kb) {
        const int ks = kb * 32;
        f32x16 s = {};
        const u16* kp = kh + (size_t)(ks + lq) * KS + hi * 8;
#pragma unroll
        for (int c = 0; c < 4; ++c) {
            s16x8 kf = *(const s16x8*)&kp[c * 16];
            s = MFMA32(kf, qf[c], s);
        }
        if (causal && kb == nkb - 1) {
#pragma unroll
            for (int r = 0; r < 16; ++r) {
                int kl = (r & 3) + 8 * (r >> 2) + 4 * hi;
                if (kl > lq) s[r] = -1e30f;
            }
        }
        float bm = fmaxf(fmaxf(fmaxf(s[0], s[1]), fmaxf(s[2], s[3])),
                         fmaxf(fmaxf(s[4], s[5]), fmaxf(s[6], s[7])));
        float bm2 = fmaxf(fmaxf(fmaxf(s[8], s[9]), fmaxf(s[10], s[11])),
                          fmaxf(fmaxf(s[12], s[13]), fmaxf(s[14], s[15])));
        bm = fmaxf(bm, bm2);
        bm = fmaxf(bm, __shfl_xor(bm, 32));
        float mn = fmaxf(mr, bm);
        float sc = __expf(mr - mn);
        mr = mn;
        float p[16];
        float rs = 0.f;
#pragma unroll
        for (int r = 0; r < 16; ++r) { p[r] = __expf(s[r] - mn); rs += p[r]; }
        rs += __shfl_xor(rs, 32);
        lr = lr * sc + rs;
#pragma unroll
        for (int r = 0; r < 16; ++r) { o0[r] *= sc; o1[r] *= sc; }

        u32 pk[8];
#pragma unroll
        for (int i = 0; i < 8; ++i)
            pk[i] = (u32)f2bf(p[2 * i]) | ((u32)f2bf(p[2 * i + 1]) << 16);
        u32 e1 = __shfl_xor(hi ? pk[0] : pk[2], 32);
        u32 e2 = __shfl_xor(hi ? pk[1] : pk[3], 32);
        u32 e3 = __shfl_xor(hi ? pk[4] : pk[6], 32);
        u32 e4 = __shfl_xor(hi ? pk[5] : pk[7], 32);
        union { s16x8 v; u32 w[4]; } pf0, pf1;
        pf0.w[0] = hi ? e1 : pk[0];
        pf0.w[1] = hi ? e2 : pk[1];
        pf0.w[2] = hi ? pk[2] : e1;
        pf0.w[3] = hi ? pk[3] : e2;
        pf1.w[0] = hi ? e3 : pk[4];
        pf1.w[1] = hi ? e4 : pk[5];
        pf1.w[2] = hi ? pk[6] : e3;
        pf1.w[3] = hi ? pk[7] : e4;

        const u16* v0 = vh + (size_t)lq * Tk + ks + hi * 8;
        const u16* v1 = vh + (size_t)(32 + lq) * Tk + ks + hi * 8;
        o0 = MFMA32(*(const s16x8*)&v0[0],  pf0.v, o0);
        o0 = MFMA32(*(const s16x8*)&v0[16], pf1.v, o0);
        o1 = MFMA32(*(const s16x8*)&v1[0],  pf0.v, o1);
        o1 = MFMA32(*(const s16x8*)&v1[16], pf1.v, o1);
    }

    float inv = 1.f / lr;
    u16* ob = oh + (size_t)(q0 + lq) * D_;
#pragma unroll
    for (int r = 0; r < 16; ++r) {
        int hd = (r & 3) + 8 * (r >> 2) + 4 * hi;
        ob[hd] = f2bf(o0[r] * inv);
        ob[hd + 32] = f2bf(o1[r] * inv);
    }
}

// ---------------- causal self-attention: paired 32-row q-tiles, uniform iters/wave
__global__ __launch_bounds__(256) void attn_causal32(const u16* __restrict__ q, const u16* __restrict__ k,
                                                     const u16* __restrict__ vT, u16* __restrict__ o,
                                                     int Tq, int Tk, int QS, int KS) {
    const int lane = threadIdx.x & 63, wid = threadIdx.x >> 6;
    const int lq = lane & 31, hi = lane >> 5;
    const int ntile = Tq / 32;            // 64
    const int ppb = (ntile / 2) / 4;      // 8 pairs per block
    const int bh = blockIdx.x / ppb;
    const int p = (blockIdx.x % ppb) * 4 + wid;
    const int b = bh >> 4, h = bh & 15;

    const u16* qh = q + ((size_t)b * Tq) * QS + h * 64;
    const u16* kh = k + ((size_t)b * Tk) * KS + h * 64;
    const u16* vh = vT + ((size_t)bh * 64) * Tk;
    u16* oh = o + ((size_t)b * Tq) * D_ + h * 64;

    const int tA = p, tB = ntile - 1 - p;
    attn32(qh, kh, vh, oh, tA * 32, tA + 1, Tk, 1, lq, hi, QS, KS);
    attn32(qh, kh, vh, oh, tB * 32, tB + 1, Tk, 1, lq, hi, QS, KS);
}

// ---------------- non-causal cross-attention: one wave per 32-row q-tile
__global__ __launch_bounds__(256) void attn_plain32(const u16* __restrict__ q, const u16* __restrict__ k,
                                                    const u16* __restrict__ vT, u16* __restrict__ o,
                                                    int Tq, int Tk, int QS, int KS) {
    const int lane = threadIdx.x & 63, wid = threadIdx.x >> 6;
    const int lq = lane & 31, hi = lane >> 5;
    const int tpb = (Tq / 32) / 4;        // 16 tiles per block
    const int bh = blockIdx.x / tpb;
    const int qt = (blockIdx.x % tpb) * 4 + wid;
    const int b = bh >> 4, h = bh & 15;

    const u16* qh = q + ((size_t)b * Tq) * QS + h * 64;
    const u16* kh = k + ((size_t)b * Tk) * KS + h * 64;
    const u16* vh = vT + ((size_t)bh * 64) * Tk;
    u16* oh = o + ((size_t)b * Tq) * D_ + h * 64;

    attn32(qh, kh, vh, oh, qt * 32, Tk / 32, Tk, 0, lq, hi, QS, KS);
}

// ---------------- fused residual add + RMSNorm: one WAVE per row, 4x float4 per lane
__global__ __launch_bounds__(256) void addnorm(const float* __restrict__ xa, const float* __restrict__ xb,
                                               const float* __restrict__ gg, float* __restrict__ fo,
                                               u16* __restrict__ bo) {
    int row = blockIdx.x * 4 + (threadIdx.x >> 6);
    int lane = threadIdx.x & 63;
    const float4* pa = (const float4*)(xa + (size_t)row * D_);
    const float4* pb = (const float4*)(xb + (size_t)row * D_);
    float4 v[4];
    float ss = 0.f;
#pragma unroll
    for (int j = 0; j < 4; ++j) {
        float4 a = pa[lane + 64 * j];
        float4 b = pb[lane + 64 * j];
        v[j].x = a.x + b.x; v[j].y = a.y + b.y; v[j].z = a.z + b.z; v[j].w = a.w + b.w;
        ss += v[j].x * v[j].x + v[j].y * v[j].y + v[j].z * v[j].z + v[j].w * v[j].w;
    }
    ss += __shfl_xor(ss, 1);
    ss += __shfl_xor(ss, 2);
    ss += __shfl_xor(ss, 4);
    ss += __shfl_xor(ss, 8);
    ss += __shfl_xor(ss, 16);
    ss += __shfl_xor(ss, 32);
    float s = rsqrtf(ss * (1.0f / D_) + 1e-6f);
#pragma unroll
    for (int j = 0; j < 4; ++j) {
        float4 gv = ((const float4*)gg)[lane + 64 * j];
        float yx = v[j].x * s * gv.x, yy = v[j].y * s * gv.y;
        float yz = v[j].z * s * gv.z, yw = v[j].w * s * gv.w;
        if (fo) {
            float4 o4; o4.x = yx; o4.y = yy; o4.z = yz; o4.w = yw;
            ((float4*)(fo + (size_t)row * D_))[lane + 64 * j] = o4;
        }
        if (bo) {
            u64 pk = (u64)f2bf(yx) | ((u64)f2bf(yy) << 16) | ((u64)f2bf(yz) << 32) | ((u64)f2bf(yw) << 48);
            ((u64*)(bo + (size_t)row * D_))[lane + 64 * j] = pk;
        }
    }
}

extern "C" void kernel_launch(void* const* d_in, const int* in_sizes, int n_in,
                              void* d_out, int out_size, void* d_ws, size_t ws_size,
                              hipStream_t stream) {
    const float* x    = (const float*)d_in[0];
    const float* mem  = (const float*)d_in[1];
    const float* fr   = (const float*)d_in[2];
    const float* wsaq = (const float*)d_in[4];
    const float* wsak = (const float*)d_in[5];
    const float* wsav = (const float*)d_in[6];
    const float* wsao = (const float*)d_in[7];
    const float* wcaq = (const float*)d_in[8];
    const float* wcak = (const float*)d_in[9];
    const float* wcav = (const float*)d_in[10];
    const float* wcao = (const float*)d_in[11];
    const float* w1   = (const float*)d_in[12];
    const float* w3   = (const float*)d_in[13];
    const float* w2   = (const float*)d_in[14];
    const float* g_sa = (const float*)d_in[15];
    const float* g_ca = (const float*)d_in[16];
    const float* g_ff = (const float*)d_in[17];
    float* outF = (float*)d_out;

    char* p = (char*)d_ws;
    auto alloc = [&](size_t bytes) { char* r = p; p += (bytes + 255) & ~(size_t)255; return r; };
    const size_t DD2 = (size_t)1024 * 1024 * 2;
    u16* wqkvT = (u16*)alloc(3 * DD2);                 // [3072][1024] fused q|k|v
    u16* saoT  = (u16*)alloc(DD2);
    u16* caqT  = (u16*)alloc(DD2);
    u16* wkvT  = (u16*)alloc(2 * DD2);                 // [2048][1024] fused k|v (CA)
    u16* caoT  = (u16*)alloc(DD2);
    u16* w1T   = (u16*)alloc((size_t)HIDP_ * 1024 * 2);
    u16* w3T   = (u16*)alloc((size_t)HIDP_ * 1024 * 2);
    u16* w2T   = (u16*)alloc((size_t)1024 * HIDP_ * 2);
    u16* Ab    = (u16*)alloc((size_t)8192 * 1024 * 2);
    u16* memb  = (u16*)alloc((size_t)2048 * 1024 * 2);
    char* qkvRaw = alloc((size_t)8192 * 3072 * 2);     // SA fused q|k|v [8192][3072]
    u16* qkvb = (u16*)qkvRaw;
    u16* kvb  = (u16*)qkvRaw;                          // CA k|v [2048][2048] (aliased; used after SA)
    u16* caqb = (u16*)(qkvRaw + (size_t)25165824);     // CA q [8192][1024] (aliased upper region)
    u16* vtb  = (u16*)alloc((size_t)8192 * 1024 * 2);
    u16* ob   = (u16*)alloc((size_t)8192 * 1024 * 2);
    float* Pf = (float*)alloc((size_t)8192 * 1024 * 4);
    float* Rf = (float*)alloc((size_t)8192 * 1024 * 4);
    u16* Hb   = (u16*)alloc((size_t)8192 * HIDP_ * 2);

    dim3 blk(256);

    // weight prep (fused QKV rows: q 0-1023 | k 1024-2047 | v 2048-3071)
    wt_cast<<<dim3(32, 32), blk, 0, stream>>>(wsaq, wqkvT,               1024, 1024, 1024, 1024);
    wt_cast<<<dim3(32, 32), blk, 0, stream>>>(wsak, wqkvT + 1024 * 1024, 1024, 1024, 1024, 1024);
    wt_cast<<<dim3(32, 32), blk, 0, stream>>>(wsav, wqkvT + 2048 * 1024, 1024, 1024, 1024, 1024);
    wt_cast<<<dim3(32, 32), blk, 0, stream>>>(wsao, saoT, 1024, 1024, 1024, 1024);
    wt_cast<<<dim3(32, 32), blk, 0, stream>>>(wcaq, caqT, 1024, 1024, 1024, 1024);
    wt_cast<<<dim3(32, 32), blk, 0, stream>>>(wcak, wkvT,               1024, 1024, 1024, 1024);
    wt_cast<<<dim3(32, 32), blk, 0, stream>>>(wcav, wkvT + 1024 * 1024, 1024, 1024, 1024, 1024);
    wt_cast<<<dim3(32, 32), blk, 0, stream>>>(wcao, caoT, 1024, 1024, 1024, 1024);
    wt_cast<<<dim3(88, 32), blk, 0, stream>>>(w1, w1T, 1024, HID_, 1024, HIDP_);
    wt_cast<<<dim3(88, 32), blk, 0, stream>>>(w3, w3T, 1024, HID_, 1024, HIDP_);
    wt_cast<<<dim3(32, 88), blk, 0, stream>>>(w2, w2T, HID_, 1024, HIDP_, 1024);

    cast_bf16<<<8192, blk, 0, stream>>>(x, Ab, 2097152);
    cast_bf16<<<2048, blk, 0, stream>>>(mem, memb, 524288);

    // ---- self-attention (fused QKV projection, N=3072)
    gemm_bf16<<<1536, blk, 0, stream>>>(Ab, wqkvT, qkvb, nullptr, 8192, 3072, 1024, 1, 1536);
    rope_qk<<<16384, blk, 0, stream>>>(qkvb, qkvb + 1024, fr, 3072);
    vtrans<<<dim3(64, 64, 2), blk, 0, stream>>>(qkvb + 2048, vtb, 2048, 3072);
    attn_causal32<<<512, blk, 0, stream>>>(qkvb, qkvb + 1024, vtb, ob, 2048, 2048, 3072, 3072);
    gemm_bf16<<<512, blk, 0, stream>>>(ob, saoT, Pf, nullptr, 8192, 1024, 1024, 0, 512);
    addnorm<<<2048, blk, 0, stream>>>(x, Pf, g_sa, Rf, Ab);

    // ---- cross-attention (fused KV projection, N=2048; q scaled via mode 4)
    gemm_bf16<<<512, blk, 0, stream>>>(Ab, caqT, caqb, nullptr, 8192, 1024, 1024, 4, 512);
    gemm_bf16<<<256, blk, 0, stream>>>(memb, wkvT, kvb, nullptr, 2048, 2048, 1024, 1, 256);
    vtrans<<<dim3(64, 16, 2), blk, 0, stream>>>(kvb + 1024, vtb, 512, 2048);
    attn_plain32<<<1024, blk, 0, stream>>>(caqb, kvb, vtb, ob, 2048, 512, 1024, 2048);
    gemm_bf16<<<512, blk, 0, stream>>>(ob, caoT, Pf, nullptr, 8192, 1024, 1024, 0, 512);
    addnorm<<<2048, blk, 0, stream>>>(Rf, Pf, g_ca, Rf, Ab);

    // ---- FFN (SwiGLU): fused w1+w3 -> H, then down-proj
    gemm_w13<<<1408, blk, 0, stream>>>(Ab, w1T, w3T, Hb, 8192, HIDP_, 1024, 1408);
    gemm_bf16<<<512, blk, 0, stream>>>(Hb, w2T, Pf, nullptr, 8192, 1024, HIDP_, 0, 512);
    addnorm<<<2048, blk, 0, stream>>>(Rf, Pf, g_ff, outF, nullptr);
}

// Round 14
// 801.886 us; speedup vs baseline: 1.4080x; 1.0698x over previous
//
#include <hip/hip_runtime.h>
#include <hip/hip_bf16.h>

typedef __attribute__((ext_vector_type(8))) short s16x8;
typedef __attribute__((ext_vector_type(4))) float f32x4;
typedef __attribute__((ext_vector_type(16))) float f32x16;
typedef unsigned short u16;
typedef unsigned int u32;
typedef unsigned long long u64;

#define MFMA(a,b,c) __builtin_amdgcn_mfma_f32_16x16x32_bf16(a,b,c,0,0,0)
#define MFMA32(a,b,c) __builtin_amdgcn_mfma_f32_32x32x16_bf16(a,b,c,0,0,0)

constexpr int B_ = 4, T_ = 2048, TKV_ = 512, D_ = 1024, H_ = 16, HD_ = 64;
constexpr int HID_ = 2736, HIDP_ = 2816; // padded to 22*128

__device__ __forceinline__ float bf2f(u16 x) {
    union { float f; u32 u; } c; c.u = ((u32)x) << 16; return c.f;
}
__device__ __forceinline__ u16 f2bf(float f) {
    union { float f; u32 u; } c; c.f = f;
    u32 r = c.u + 0x7fffu + ((c.u >> 16) & 1u);
    return (u16)(r >> 16);
}

__device__ __forceinline__ void gload16(const void* g, void* l) {
    __builtin_amdgcn_global_load_lds(
        (const __attribute__((address_space(1))) u32*)g,
        (__attribute__((address_space(3))) u32*)l, 16, 0, 0);
}

// ---------------- weight transpose + cast:  W[K,N] f32 -> WT[Np,Kp] bf16 (zero-padded)
__global__ __launch_bounds__(256) void wt_cast(const float* __restrict__ W, u16* __restrict__ WT,
                                               int K, int N, int Kp, int Np) {
    __shared__ float t[32][33];
    int tid = threadIdx.x;
    int tx = tid & 31, ty = tid >> 5;
    int n0 = blockIdx.x * 32, k0 = blockIdx.y * 32;
#pragma unroll
    for (int i = 0; i < 4; ++i) {
        int kk = k0 + ty + i * 8, nn = n0 + tx;
        t[ty + i * 8][tx] = (kk < K && nn < N) ? W[(size_t)kk * N + nn] : 0.f;
    }
    __syncthreads();
#pragma unroll
    for (int i = 0; i < 4; ++i) {
        int nn = n0 + ty + i * 8, kk = k0 + tx;
        WT[(size_t)nn * Kp + kk] = f2bf(t[tx][ty + i * 8]);
    }
}

// ---------------- f32 -> bf16 cast (4 elems/thread)
__global__ __launch_bounds__(256) void cast_bf16(const float* __restrict__ in, u16* __restrict__ out, int n4) {
    int i = blockIdx.x * 256 + threadIdx.x;
    if (i >= n4) return;
    float4 v = ((const float4*)in)[i];
    u64 pk = (u64)f2bf(v.x) | ((u64)f2bf(v.y) << 16) | ((u64)f2bf(v.z) << 32) | ((u64)f2bf(v.w) << 48);
    ((u64*)out)[i] = pk;
}

// ---------------- epilogue store helper
__device__ __forceinline__ void gemm_store(void* C, const u16* mul, size_t idx, float v, int mode) {
    if (mode == 0) {
        ((float*)C)[idx] = v;
    } else if (mode == 1) {
        ((u16*)C)[idx] = f2bf(v);
    } else if (mode == 2) {
        float sg = 1.f / (1.f + __expf(-v));
        ((u16*)C)[idx] = f2bf(v * sg);
    } else if (mode == 3) {
        float h = bf2f(mul[idx]);
        ((u16*)C)[idx] = f2bf(v * h);
    } else {
        ((u16*)C)[idx] = f2bf(v * 0.125f);
    }
}

// LDS slot swizzle (T2, rule #21): physical 16B-slot p of row r holds logical
// slot p^(r&7); staged via inverse-permuted GLOBAL source (LDS dest linear for
// global_load_lds); reads apply the same XOR.

// ---------------- GEMM 128x128 tile, 4 waves, SINGLE-buffered (32 KiB LDS), slot-swizzled.
// (r9 proven structure, m-major decode; inter-block overlap hides the stage drain)
__global__ __launch_bounds__(256) void gemm_bf16(const u16* __restrict__ A, const u16* __restrict__ Bt,
                                                 void* __restrict__ C, const u16* __restrict__ mul,
                                                 int M, int N, int K, int mode, int nwg) {
    __shared__ __align__(16) u16 As[128 * 64];
    __shared__ __align__(16) u16 Bs[128 * 64];
    const int tid = threadIdx.x;
    const int lane = tid & 63, wid = tid >> 6;
    const int wr = wid >> 1, wc = wid & 1;
    const int li = lane & 15, g = lane >> 4;

    int bid = (int)blockIdx.x;
    bid = (bid & 7) * (nwg >> 3) + (bid >> 3);

    const int tn = N >> 7;
    const int m0 = (bid / tn) * 128, n0 = (bid % tn) * 128;   // m-major (r9)

    const int rowst = tid >> 3;
    const int colb = (((tid & 7) ^ ((tid >> 3) & 7)) * 16);   // inverse-swizzled source slot
    const char* ga = (const char*)A + ((size_t)(m0 + rowst) * K) * 2 + colb;
    const char* gb = (const char*)Bt + ((size_t)(n0 + rowst) * K) * 2 + colb;
    const size_t rstride = (size_t)32 * K * 2;

    f32x4 acc[4][4] = {};
    const int nt = K >> 6;

    for (int t = 0; t < nt; ++t) {
#pragma unroll
        for (int i = 0; i < 4; ++i) {
            gload16(ga + (size_t)t * 128 + i * rstride, (char*)As + i * 4096 + wid * 1024);
            gload16(gb + (size_t)t * 128 + i * rstride, (char*)Bs + i * 4096 + wid * 1024);
        }
        __syncthreads();
#pragma unroll
        for (int kk = 0; kk < 2; ++kk) {
            s16x8 aF[4], bF[4];
            const int sl = ((kk << 2) | g) ^ (li & 7);
#pragma unroll
            for (int m = 0; m < 4; ++m) aF[m] = *(const s16x8*)&As[(wr * 64 + m * 16 + li) * 64 + sl * 8];
#pragma unroll
            for (int n = 0; n < 4; ++n) bF[n] = *(const s16x8*)&Bs[(wc * 64 + n * 16 + li) * 64 + sl * 8];
#pragma unroll
            for (int m = 0; m < 4; ++m)
#pragma unroll
                for (int n = 0; n < 4; ++n)
                    acc[m][n] = MFMA(aF[m], bF[n], acc[m][n]);
        }
        __syncthreads();
    }

#pragma unroll
    for (int m = 0; m < 4; ++m)
#pragma unroll
        for (int n = 0; n < 4; ++n)
#pragma unroll
            for (int r = 0; r < 4; ++r) {
                size_t row = m0 + wr * 64 + m * 16 + g * 4 + r;
                size_t col = n0 + wc * 64 + n * 16 + li;
                gemm_store(C, mul, row * N + col, acc[m][n][r], mode);
            }
}

// ---------------- fused SwiGLU hidden GEMM: H = silu(A@W1t^T) * (A@W3t^T).
// r9 version (425 TF): A,B1,B3 all LDS-staged (48 KiB), 12 loads/thread/K-tile, m-major.
__global__ __launch_bounds__(256) void gemm_w13(const u16* __restrict__ A, const u16* __restrict__ B1t,
                                                const u16* __restrict__ B3t, u16* __restrict__ Hout,
                                                int M, int N, int K, int nwg) {
    __shared__ __align__(16) u16 As[128 * 64];
    __shared__ __align__(16) u16 B1s[128 * 64];
    __shared__ __align__(16) u16 B3s[128 * 64];
    const int tid = threadIdx.x;
    const int lane = tid & 63, wid = tid >> 6;
    const int wr = wid >> 1, wc = wid & 1;
    const int li = lane & 15, g = lane >> 4;

    int bid = (int)blockIdx.x;
    bid = (bid & 7) * (nwg >> 3) + (bid >> 3);

    const int tn = N >> 7;
    const int m0 = (bid / tn) * 128, n0 = (bid % tn) * 128;   // m-major (r9)

    const int rowst = tid >> 3;
    const int colb = (((tid & 7) ^ ((tid >> 3) & 7)) * 16);
    const char* ga = (const char*)A + ((size_t)(m0 + rowst) * K) * 2 + colb;
    const char* gb1 = (const char*)B1t + ((size_t)(n0 + rowst) * K) * 2 + colb;
    const char* gb3 = (const char*)B3t + ((size_t)(n0 + rowst) * K) * 2 + colb;
    const size_t rstride = (size_t)32 * K * 2;

    f32x4 acc1[4][4] = {}, acc3[4][4] = {};
    const int nt = K >> 6;

    for (int t = 0; t < nt; ++t) {
#pragma unroll
        for (int i = 0; i < 4; ++i) {
            gload16(ga + (size_t)t * 128 + i * rstride, (char*)As + i * 4096 + wid * 1024);
            gload16(gb1 + (size_t)t * 128 + i * rstride, (char*)B1s + i * 4096 + wid * 1024);
            gload16(gb3 + (size_t)t * 128 + i * rstride, (char*)B3s + i * 4096 + wid * 1024);
        }
        __syncthreads();
#pragma unroll
        for (int kk = 0; kk < 2; ++kk) {
            const int sl = ((kk << 2) | g) ^ (li & 7);
            s16x8 aF[4];
#pragma unroll
            for (int m = 0; m < 4; ++m) aF[m] = *(const s16x8*)&As[(wr * 64 + m * 16 + li) * 64 + sl * 8];
            {   // W1 product
                s16x8 bF[4];
#pragma unroll
                for (int n = 0; n < 4; ++n) bF[n] = *(const s16x8*)&B1s[(wc * 64 + n * 16 + li) * 64 + sl * 8];
#pragma unroll
                for (int m = 0; m < 4; ++m)
#pragma unroll
                    for (int n = 0; n < 4; ++n)
                        acc1[m][n] = MFMA(aF[m], bF[n], acc1[m][n]);
            }
            {   // W3 product
                s16x8 bF[4];
#pragma unroll
                for (int n = 0; n < 4; ++n) bF[n] = *(const s16x8*)&B3s[(wc * 64 + n * 16 + li) * 64 + sl * 8];
#pragma unroll
                for (int m = 0; m < 4; ++m)
#pragma unroll
                    for (int n = 0; n < 4; ++n)
                        acc3[m][n] = MFMA(aF[m], bF[n], acc3[m][n]);
            }
        }
        __syncthreads();
    }

#pragma unroll
    for (int m = 0; m < 4; ++m)
#pragma unroll
        for (int n = 0; n < 4; ++n)
#pragma unroll
            for (int r = 0; r < 4; ++r) {
                size_t row = m0 + wr * 64 + m * 16 + g * 4 + r;
                size_t col = n0 + wc * 64 + n * 16 + li;
                float h1 = acc1[m][n][r];
                float h3 = acc3[m][n][r];
                float sg = 1.f / (1.f + __expf(-h1));
                Hout[row * N + col] = f2bf(h1 * sg * h3);
            }
}

// ---------------- RoPE in-place on q and k (strided); q additionally scaled by 0.125
__global__ __launch_bounds__(256) void rope_qk(u16* __restrict__ q, u16* __restrict__ k,
                                               const float* __restrict__ fr, int S) {
    size_t idx = (size_t)blockIdx.x * 256 + threadIdx.x; // over B*T*H*(HD/2)
    int i = (int)(idx & 31);
    int h = (int)((idx >> 5) & 15);
    size_t bt = idx >> 9;             // b*T + t
    int t = (int)(bt & (T_ - 1));
    float2 cs = ((const float2*)fr)[t * 32 + i];
    size_t off = bt * (size_t)S + h * 64 + 2 * i;
    {
        u32* p = (u32*)(q + off);
        u32 w = *p;
        float a = bf2f((u16)(w & 0xffff)), b = bf2f((u16)(w >> 16));
        *p = (u32)f2bf((a * cs.x - b * cs.y) * 0.125f) | ((u32)f2bf((a * cs.y + b * cs.x) * 0.125f) << 16);
    }
    {
        u32* p = (u32*)(k + off);
        u32 w = *p;
        float a = bf2f((u16)(w & 0xffff)), b = bf2f((u16)(w >> 16));
        *p = (u32)f2bf(a * cs.x - b * cs.y) | ((u32)f2bf(a * cs.y + b * cs.x) << 16);
    }
}

// ---------------- V transpose: v[B,Tk,*] (stride S) bf16 -> vT[B,H,HD,Tk] bf16
__global__ __launch_bounds__(256) void vtrans(const u16* __restrict__ v, u16* __restrict__ vT,
                                              int Tk, int S) {
    __shared__ u16 tile[32][34];
    int bh = blockIdx.x;
    int t0 = blockIdx.y * 32, d0 = blockIdx.z * 32;
    int b = bh >> 4, h = bh & 15;
    int tid = threadIdx.x;
    int tx = tid & 31, ty = tid >> 5;
#pragma unroll
    for (int i = 0; i < 4; ++i)
        tile[ty + i * 8][tx] = v[((size_t)b * Tk + t0 + ty + i * 8) * S + h * 64 + d0 + tx];
    __syncthreads();
#pragma unroll
    for (int i = 0; i < 4; ++i)
        vT[((size_t)bh * 64 + d0 + ty + i * 8) * Tk + t0 + tx] = tile[tx][ty + i * 8];
}

// ---------------- swapped-QK^T 32x32 attention tile: one wave = 32 q rows.
__device__ __forceinline__ void attn32(const u16* __restrict__ qh, const u16* __restrict__ kh,
                                       const u16* __restrict__ vh, u16* __restrict__ oh,
                                       int q0, int nkb, int Tk, int causal, int lq, int hi,
                                       int QS, int KS) {
    const u16* qb = qh + (size_t)(q0 + lq) * QS;
    s16x8 qf[4];
#pragma unroll
    for (int c = 0; c < 4; ++c) qf[c] = *(const s16x8*)&qb[c * 16 + hi * 8];

    f32x16 o0 = {}, o1 = {};
    float mr = -1e30f, lr = 0.f;

    for (int kb = 0; kb < nkb; ++kb) {
        const int ks = kb * 32;
        f32x16 s = {};
        const u16* kp = kh + (size_t)(ks + lq) * KS + hi * 8;
#pragma unroll
        for (int c = 0; c < 4; ++c) {
            s16x8 kf = *(const s16x8*)&kp[c * 16];
            s = MFMA32(kf, qf[c], s);
        }
        if (causal && kb == nkb - 1) {
#pragma unroll
            for (int r = 0; r < 16; ++r) {
                int kl = (r & 3) + 8 * (r >> 2) + 4 * hi;
                if (kl > lq) s[r] = -1e30f;
            }
        }
        float bm = fmaxf(fmaxf(fmaxf(s[0], s[1]), fmaxf(s[2], s[3])),
                         fmaxf(fmaxf(s[4], s[5]), fmaxf(s[6], s[7])));
        float bm2 = fmaxf(fmaxf(fmaxf(s[8], s[9]), fmaxf(s[10], s[11])),
                          fmaxf(fmaxf(s[12], s[13]), fmaxf(s[14], s[15])));
        bm = fmaxf(bm, bm2);
        bm = fmaxf(bm, __shfl_xor(bm, 32));
        float mn = fmaxf(mr, bm);
        float sc = __expf(mr - mn);
        mr = mn;
        float p[16];
        float rs = 0.f;
#pragma unroll
        for (int r = 0; r < 16; ++r) { p[r] = __expf(s[r] - mn); rs += p[r]; }
        rs += __shfl_xor(rs, 32);
        lr = lr * sc + rs;
#pragma unroll
        for (int r = 0; r < 16; ++r) { o0[r] *= sc; o1[r] *= sc; }

        u32 pk[8];
#pragma unroll
        for (int i = 0; i < 8; ++i)
            pk[i] = (u32)f2bf(p[2 * i]) | ((u32)f2bf(p[2 * i + 1]) << 16);
        u32 e1 = __shfl_xor(hi ? pk[0] : pk[2], 32);
        u32 e2 = __shfl_xor(hi ? pk[1] : pk[3], 32);
        u32 e3 = __shfl_xor(hi ? pk[4] : pk[6], 32);
        u32 e4 = __shfl_xor(hi ? pk[5] : pk[7], 32);
        union { s16x8 v; u32 w[4]; } pf0, pf1;
        pf0.w[0] = hi ? e1 : pk[0];
        pf0.w[1] = hi ? e2 : pk[1];
        pf0.w[2] = hi ? pk[2] : e1;
        pf0.w[3] = hi ? pk[3] : e2;
        pf1.w[0] = hi ? e3 : pk[4];
        pf1.w[1] = hi ? e4 : pk[5];
        pf1.w[2] = hi ? pk[6] : e3;
        pf1.w[3] = hi ? pk[7] : e4;

        const u16* v0 = vh + (size_t)lq * Tk + ks + hi * 8;
        const u16* v1 = vh + (size_t)(32 + lq) * Tk + ks + hi * 8;
        o0 = MFMA32(*(const s16x8*)&v0[0],  pf0.v, o0);
        o0 = MFMA32(*(const s16x8*)&v0[16], pf1.v, o0);
        o1 = MFMA32(*(const s16x8*)&v1[0],  pf0.v, o1);
        o1 = MFMA32(*(const s16x8*)&v1[16], pf1.v, o1);
    }

    float inv = 1.f / lr;
    u16* ob = oh + (size_t)(q0 + lq) * D_;
#pragma unroll
    for (int r = 0; r < 16; ++r) {
        int hd = (r & 3) + 8 * (r >> 2) + 4 * hi;
        ob[hd] = f2bf(o0[r] * inv);
        ob[hd + 32] = f2bf(o1[r] * inv);
    }
}

// ---------------- causal self-attention: paired 32-row q-tiles, uniform iters/wave
__global__ __launch_bounds__(256) void attn_causal32(const u16* __restrict__ q, const u16* __restrict__ k,
                                                     const u16* __restrict__ vT, u16* __restrict__ o,
                                                     int Tq, int Tk, int QS, int KS) {
    const int lane = threadIdx.x & 63, wid = threadIdx.x >> 6;
    const int lq = lane & 31, hi = lane >> 5;
    const int ntile = Tq / 32;            // 64
    const int ppb = (ntile / 2) / 4;      // 8 pairs per block
    const int bh = blockIdx.x / ppb;
    const int p = (blockIdx.x % ppb) * 4 + wid;
    const int b = bh >> 4, h = bh & 15;

    const u16* qh = q + ((size_t)b * Tq) * QS + h * 64;
    const u16* kh = k + ((size_t)b * Tk) * KS + h * 64;
    const u16* vh = vT + ((size_t)bh * 64) * Tk;
    u16* oh = o + ((size_t)b * Tq) * D_ + h * 64;

    const int tA = p, tB = ntile - 1 - p;
    attn32(qh, kh, vh, oh, tA * 32, tA + 1, Tk, 1, lq, hi, QS, KS);
    attn32(qh, kh, vh, oh, tB * 32, tB + 1, Tk, 1, lq, hi, QS, KS);
}

// ---------------- non-causal cross-attention: one wave per 32-row q-tile
__global__ __launch_bounds__(256) void attn_plain32(const u16* __restrict__ q, const u16* __restrict__ k,
                                                    const u16* __restrict__ vT, u16* __restrict__ o,
                                                    int Tq, int Tk, int QS, int KS) {
    const int lane = threadIdx.x & 63, wid = threadIdx.x >> 6;
    const int lq = lane & 31, hi = lane >> 5;
    const int tpb = (Tq / 32) / 4;        // 16 tiles per block
    const int bh = blockIdx.x / tpb;
    const int qt = (blockIdx.x % tpb) * 4 + wid;
    const int b = bh >> 4, h = bh & 15;

    const u16* qh = q + ((size_t)b * Tq) * QS + h * 64;
    const u16* kh = k + ((size_t)b * Tk) * KS + h * 64;
    const u16* vh = vT + ((size_t)bh * 64) * Tk;
    u16* oh = o + ((size_t)b * Tq) * D_ + h * 64;

    attn32(qh, kh, vh, oh, qt * 32, Tk / 32, Tk, 0, lq, hi, QS, KS);
}

// ---------------- fused residual add + RMSNorm: one WAVE per row, 4x float4 per lane.
// xb is now bf16 (GEMM epilogue writes mode 1): halves the non-residual stream.
__global__ __launch_bounds__(256) void addnorm(const float* __restrict__ xa, const u16* __restrict__ xb,
                                               const float* __restrict__ gg, float* __restrict__ fo,
                                               u16* __restrict__ bo) {
    int row = blockIdx.x * 4 + (threadIdx.x >> 6);
    int lane = threadIdx.x & 63;
    const float4* pa = (const float4*)(xa + (size_t)row * D_);
    const u64* pb = (const u64*)(xb + (size_t)row * D_);
    float4 v[4];
    float ss = 0.f;
#pragma unroll
    for (int j = 0; j < 4; ++j) {
        float4 a = pa[lane + 64 * j];
        u64 bw = pb[lane + 64 * j];
        v[j].x = a.x + bf2f((u16)(bw));
        v[j].y = a.y + bf2f((u16)(bw >> 16));
        v[j].z = a.z + bf2f((u16)(bw >> 32));
        v[j].w = a.w + bf2f((u16)(bw >> 48));
        ss += v[j].x * v[j].x + v[j].y * v[j].y + v[j].z * v[j].z + v[j].w * v[j].w;
    }
    ss += __shfl_xor(ss, 1);
    ss += __shfl_xor(ss, 2);
    ss += __shfl_xor(ss, 4);
    ss += __shfl_xor(ss, 8);
    ss += __shfl_xor(ss, 16);
    ss += __shfl_xor(ss, 32);
    float s = rsqrtf(ss * (1.0f / D_) + 1e-6f);
#pragma unroll
    for (int j = 0; j < 4; ++j) {
        float4 gv = ((const float4*)gg)[lane + 64 * j];
        float yx = v[j].x * s * gv.x, yy = v[j].y * s * gv.y;
        float yz = v[j].z * s * gv.z, yw = v[j].w * s * gv.w;
        if (fo) {
            float4 o4; o4.x = yx; o4.y = yy; o4.z = yz; o4.w = yw;
            ((float4*)(fo + (size_t)row * D_))[lane + 64 * j] = o4;
        }
        if (bo) {
            u64 pk = (u64)f2bf(yx) | ((u64)f2bf(yy) << 16) | ((u64)f2bf(yz) << 32) | ((u64)f2bf(yw) << 48);
            ((u64*)(bo + (size_t)row * D_))[lane + 64 * j] = pk;
        }
    }
}

extern "C" void kernel_launch(void* const* d_in, const int* in_sizes, int n_in,
                              void* d_out, int out_size, void* d_ws, size_t ws_size,
                              hipStream_t stream) {
    const float* x    = (const float*)d_in[0];
    const float* mem  = (const float*)d_in[1];
    const float* fr   = (const float*)d_in[2];
    const float* wsaq = (const float*)d_in[4];
    const float* wsak = (const float*)d_in[5];
    const float* wsav = (const float*)d_in[6];
    const float* wsao = (const float*)d_in[7];
    const float* wcaq = (const float*)d_in[8];
    const float* wcak = (const float*)d_in[9];
    const float* wcav = (const float*)d_in[10];
    const float* wcao = (const float*)d_in[11];
    const float* w1   = (const float*)d_in[12];
    const float* w3   = (const float*)d_in[13];
    const float* w2   = (const float*)d_in[14];
    const float* g_sa = (const float*)d_in[15];
    const float* g_ca = (const float*)d_in[16];
    const float* g_ff = (const float*)d_in[17];
    float* outF = (float*)d_out;

    char* p = (char*)d_ws;
    auto alloc = [&](size_t bytes) { char* r = p; p += (bytes + 255) & ~(size_t)255; return r; };
    const size_t DD2 = (size_t)1024 * 1024 * 2;
    u16* wqkvT = (u16*)alloc(3 * DD2);                 // [3072][1024] fused q|k|v
    u16* saoT  = (u16*)alloc(DD2);
    u16* caqT  = (u16*)alloc(DD2);
    u16* wkvT  = (u16*)alloc(2 * DD2);                 // [2048][1024] fused k|v (CA)
    u16* caoT  = (u16*)alloc(DD2);
    u16* w1T   = (u16*)alloc((size_t)HIDP_ * 1024 * 2);
    u16* w3T   = (u16*)alloc((size_t)HIDP_ * 1024 * 2);
    u16* w2T   = (u16*)alloc((size_t)1024 * HIDP_ * 2);
    u16* Ab    = (u16*)alloc((size_t)8192 * 1024 * 2);
    u16* memb  = (u16*)alloc((size_t)2048 * 1024 * 2);
    char* qkvRaw = alloc((size_t)8192 * 3072 * 2);     // SA fused q|k|v [8192][3072]
    u16* qkvb = (u16*)qkvRaw;
    u16* kvb  = (u16*)qkvRaw;                          // CA k|v [2048][2048] (aliased; used after SA)
    u16* caqb = (u16*)(qkvRaw + (size_t)25165824);     // CA q [8192][1024] (aliased upper region)
    u16* vtb  = (u16*)alloc((size_t)8192 * 1024 * 2);
    u16* ob   = (u16*)alloc((size_t)8192 * 1024 * 2);
    u16* Pb   = (u16*)alloc((size_t)8192 * 1024 * 2);  // bf16 GEMM->addnorm intermediate
    float* Rf = (float*)alloc((size_t)8192 * 1024 * 4);
    u16* Hb   = (u16*)alloc((size_t)8192 * HIDP_ * 2);

    dim3 blk(256);

    // weight prep (fused QKV rows: q 0-1023 | k 1024-2047 | v 2048-3071)
    wt_cast<<<dim3(32, 32), blk, 0, stream>>>(wsaq, wqkvT,               1024, 1024, 1024, 1024);
    wt_cast<<<dim3(32, 32), blk, 0, stream>>>(wsak, wqkvT + 1024 * 1024, 1024, 1024, 1024, 1024);
    wt_cast<<<dim3(32, 32), blk, 0, stream>>>(wsav, wqkvT + 2048 * 1024, 1024, 1024, 1024, 1024);
    wt_cast<<<dim3(32, 32), blk, 0, stream>>>(wsao, saoT, 1024, 1024, 1024, 1024);
    wt_cast<<<dim3(32, 32), blk, 0, stream>>>(wcaq, caqT, 1024, 1024, 1024, 1024);
    wt_cast<<<dim3(32, 32), blk, 0, stream>>>(wcak, wkvT,               1024, 1024, 1024, 1024);
    wt_cast<<<dim3(32, 32), blk, 0, stream>>>(wcav, wkvT + 1024 * 1024, 1024, 1024, 1024, 1024);
    wt_cast<<<dim3(32, 32), blk, 0, stream>>>(wcao, caoT, 1024, 1024, 1024, 1024);
    wt_cast<<<dim3(88, 32), blk, 0, stream>>>(w1, w1T, 1024, HID_, 1024, HIDP_);
    wt_cast<<<dim3(88, 32), blk, 0, stream>>>(w3, w3T, 1024, HID_, 1024, HIDP_);
    wt_cast<<<dim3(32, 88), blk, 0, stream>>>(w2, w2T, HID_, 1024, HIDP_, 1024);

    cast_bf16<<<8192, blk, 0, stream>>>(x, Ab, 2097152);
    cast_bf16<<<2048, blk, 0, stream>>>(mem, memb, 524288);

    // ---- self-attention (fused QKV projection, N=3072)
    gemm_bf16<<<1536, blk, 0, stream>>>(Ab, wqkvT, qkvb, nullptr, 8192, 3072, 1024, 1, 1536);
    rope_qk<<<16384, blk, 0, stream>>>(qkvb, qkvb + 1024, fr, 3072);
    vtrans<<<dim3(64, 64, 2), blk, 0, stream>>>(qkvb + 2048, vtb, 2048, 3072);
    attn_causal32<<<512, blk, 0, stream>>>(qkvb, qkvb + 1024, vtb, ob, 2048, 2048, 3072, 3072);
    gemm_bf16<<<512, blk, 0, stream>>>(ob, saoT, Pb, nullptr, 8192, 1024, 1024, 1, 512);
    addnorm<<<2048, blk, 0, stream>>>(x, Pb, g_sa, Rf, Ab);

    // ---- cross-attention (fused KV projection, N=2048; q scaled via mode 4)
    gemm_bf16<<<512, blk, 0, stream>>>(Ab, caqT, caqb, nullptr, 8192, 1024, 1024, 4, 512);
    gemm_bf16<<<256, blk, 0, stream>>>(memb, wkvT, kvb, nullptr, 2048, 2048, 1024, 1, 256);
    vtrans<<<dim3(64, 16, 2), blk, 0, stream>>>(kvb + 1024, vtb, 512, 2048);
    attn_plain32<<<1024, blk, 0, stream>>>(caqb, kvb, vtb, ob, 2048, 512, 1024, 2048);
    gemm_bf16<<<512, blk, 0, stream>>>(ob, caoT, Pb, nullptr, 8192, 1024, 1024, 1, 512);
    addnorm<<<2048, blk, 0, stream>>>(Rf, Pb, g_ca, Rf, Ab);

    // ---- FFN (SwiGLU): fused w1+w3 -> H, then down-proj
    gemm_w13<<<1408, blk, 0, stream>>>(Ab, w1T, w3T, Hb, 8192, HIDP_, 1024, 1408);
    gemm_bf16<<<512, blk, 0, stream>>>(Hb, w2T, Pb, nullptr, 8192, 1024, HIDP_, 1, 512);
    addnorm<<<2048, blk, 0, stream>>>(Rf, Pb, g_ff, outF, nullptr);
}

// Round 15
// 774.587 us; speedup vs baseline: 1.4576x; 1.0352x over previous
//
#include <hip/hip_runtime.h>
#include <hip/hip_bf16.h>

typedef __attribute__((ext_vector_type(8))) short s16x8;
typedef __attribute__((ext_vector_type(4))) float f32x4;
typedef __attribute__((ext_vector_type(16))) float f32x16;
typedef unsigned short u16;
typedef unsigned int u32;
typedef unsigned long long u64;

#define MFMA(a,b,c) __builtin_amdgcn_mfma_f32_16x16x32_bf16(a,b,c,0,0,0)
#define MFMA32(a,b,c) __builtin_amdgcn_mfma_f32_32x32x16_bf16(a,b,c,0,0,0)

constexpr int B_ = 4, T_ = 2048, TKV_ = 512, D_ = 1024, H_ = 16, HD_ = 64;
constexpr int HID_ = 2736, HIDP_ = 2816; // padded to 22*128

__device__ __forceinline__ float bf2f(u16 x) {
    union { float f; u32 u; } c; c.u = ((u32)x) << 16; return c.f;
}
__device__ __forceinline__ u16 f2bf(float f) {
    union { float f; u32 u; } c; c.f = f;
    u32 r = c.u + 0x7fffu + ((c.u >> 16) & 1u);
    return (u16)(r >> 16);
}

__device__ __forceinline__ void gload16(const void* g, void* l) {
    __builtin_amdgcn_global_load_lds(
        (const __attribute__((address_space(1))) u32*)g,
        (__attribute__((address_space(3))) u32*)l, 16, 0, 0);
}

// ---------------- weight transpose + cast:  W[K,N] f32 -> WT[Np,Kp] bf16 (zero-padded)
__global__ __launch_bounds__(256) void wt_cast(const float* __restrict__ W, u16* __restrict__ WT,
                                               int K, int N, int Kp, int Np) {
    __shared__ float t[32][33];
    int tid = threadIdx.x;
    int tx = tid & 31, ty = tid >> 5;
    int n0 = blockIdx.x * 32, k0 = blockIdx.y * 32;
#pragma unroll
    for (int i = 0; i < 4; ++i) {
        int kk = k0 + ty + i * 8, nn = n0 + tx;
        t[ty + i * 8][tx] = (kk < K && nn < N) ? W[(size_t)kk * N + nn] : 0.f;
    }
    __syncthreads();
#pragma unroll
    for (int i = 0; i < 4; ++i) {
        int nn = n0 + ty + i * 8, kk = k0 + tx;
        WT[(size_t)nn * Kp + kk] = f2bf(t[tx][ty + i * 8]);
    }
}

// ---------------- f32 -> bf16 cast (4 elems/thread)
__global__ __launch_bounds__(256) void cast_bf16(const float* __restrict__ in, u16* __restrict__ out, int n4) {
    int i = blockIdx.x * 256 + threadIdx.x;
    if (i >= n4) return;
    float4 v = ((const float4*)in)[i];
    u64 pk = (u64)f2bf(v.x) | ((u64)f2bf(v.y) << 16) | ((u64)f2bf(v.z) << 32) | ((u64)f2bf(v.w) << 48);
    ((u64*)out)[i] = pk;
}

// ---------------- epilogue store helper
__device__ __forceinline__ void gemm_store(void* C, const u16* mul, size_t idx, float v, int mode) {
    if (mode == 0) {
        ((float*)C)[idx] = v;
    } else if (mode == 1) {
        ((u16*)C)[idx] = f2bf(v);
    } else if (mode == 2) {
        float sg = 1.f / (1.f + __expf(-v));
        ((u16*)C)[idx] = f2bf(v * sg);
    } else if (mode == 3) {
        float h = bf2f(mul[idx]);
        ((u16*)C)[idx] = f2bf(v * h);
    } else {
        ((u16*)C)[idx] = f2bf(v * 0.125f);
    }
}

// LDS slot swizzle (T2, rule #21): physical 16B-slot p of row r holds logical
// slot p^(r&7); staged via inverse-permuted GLOBAL source (LDS dest linear for
// global_load_lds); reads apply the same XOR.

// ---------------- GEMM 128x128 tile, 4 waves, SINGLE-buffered (32 KiB LDS), slot-swizzled.
__global__ __launch_bounds__(256) void gemm_bf16(const u16* __restrict__ A, const u16* __restrict__ Bt,
                                                 void* __restrict__ C, const u16* __restrict__ mul,
                                                 int M, int N, int K, int mode, int nwg) {
    __shared__ __align__(16) u16 As[128 * 64];
    __shared__ __align__(16) u16 Bs[128 * 64];
    const int tid = threadIdx.x;
    const int lane = tid & 63, wid = tid >> 6;
    const int wr = wid >> 1, wc = wid & 1;
    const int li = lane & 15, g = lane >> 4;

    int bid = (int)blockIdx.x;
    bid = (bid & 7) * (nwg >> 3) + (bid >> 3);

    const int tn = N >> 7;
    const int m0 = (bid / tn) * 128, n0 = (bid % tn) * 128;   // m-major (r9)

    const int rowst = tid >> 3;
    const int colb = (((tid & 7) ^ ((tid >> 3) & 7)) * 16);   // inverse-swizzled source slot
    const char* ga = (const char*)A + ((size_t)(m0 + rowst) * K) * 2 + colb;
    const char* gb = (const char*)Bt + ((size_t)(n0 + rowst) * K) * 2 + colb;
    const size_t rstride = (size_t)32 * K * 2;

    f32x4 acc[4][4] = {};
    const int nt = K >> 6;

    for (int t = 0; t < nt; ++t) {
#pragma unroll
        for (int i = 0; i < 4; ++i) {
            gload16(ga + (size_t)t * 128 + i * rstride, (char*)As + i * 4096 + wid * 1024);
            gload16(gb + (size_t)t * 128 + i * rstride, (char*)Bs + i * 4096 + wid * 1024);
        }
        __syncthreads();
#pragma unroll
        for (int kk = 0; kk < 2; ++kk) {
            s16x8 aF[4], bF[4];
            const int sl = ((kk << 2) | g) ^ (li & 7);
#pragma unroll
            for (int m = 0; m < 4; ++m) aF[m] = *(const s16x8*)&As[(wr * 64 + m * 16 + li) * 64 + sl * 8];
#pragma unroll
            for (int n = 0; n < 4; ++n) bF[n] = *(const s16x8*)&Bs[(wc * 64 + n * 16 + li) * 64 + sl * 8];
#pragma unroll
            for (int m = 0; m < 4; ++m)
#pragma unroll
                for (int n = 0; n < 4; ++n)
                    acc[m][n] = MFMA(aF[m], bF[n], acc[m][n]);
        }
        __syncthreads();
    }

#pragma unroll
    for (int m = 0; m < 4; ++m)
#pragma unroll
        for (int n = 0; n < 4; ++n)
#pragma unroll
            for (int r = 0; r < 4; ++r) {
                size_t row = m0 + wr * 64 + m * 16 + g * 4 + r;
                size_t col = n0 + wc * 64 + n * 16 + li;
                gemm_store(C, mul, row * N + col, acc[m][n][r], mode);
            }
}

// ---------------- fused SwiGLU hidden GEMM: H = silu(A@W1t^T) * (A@W3t^T).
__global__ __launch_bounds__(256) void gemm_w13(const u16* __restrict__ A, const u16* __restrict__ B1t,
                                                const u16* __restrict__ B3t, u16* __restrict__ Hout,
                                                int M, int N, int K, int nwg) {
    __shared__ __align__(16) u16 As[128 * 64];
    __shared__ __align__(16) u16 B1s[128 * 64];
    __shared__ __align__(16) u16 B3s[128 * 64];
    const int tid = threadIdx.x;
    const int lane = tid & 63, wid = tid >> 6;
    const int wr = wid >> 1, wc = wid & 1;
    const int li = lane & 15, g = lane >> 4;

    int bid = (int)blockIdx.x;
    bid = (bid & 7) * (nwg >> 3) + (bid >> 3);

    const int tn = N >> 7;
    const int m0 = (bid / tn) * 128, n0 = (bid % tn) * 128;   // m-major (r9)

    const int rowst = tid >> 3;
    const int colb = (((tid & 7) ^ ((tid >> 3) & 7)) * 16);
    const char* ga = (const char*)A + ((size_t)(m0 + rowst) * K) * 2 + colb;
    const char* gb1 = (const char*)B1t + ((size_t)(n0 + rowst) * K) * 2 + colb;
    const char* gb3 = (const char*)B3t + ((size_t)(n0 + rowst) * K) * 2 + colb;
    const size_t rstride = (size_t)32 * K * 2;

    f32x4 acc1[4][4] = {}, acc3[4][4] = {};
    const int nt = K >> 6;

    for (int t = 0; t < nt; ++t) {
#pragma unroll
        for (int i = 0; i < 4; ++i) {
            gload16(ga + (size_t)t * 128 + i * rstride, (char*)As + i * 4096 + wid * 1024);
            gload16(gb1 + (size_t)t * 128 + i * rstride, (char*)B1s + i * 4096 + wid * 1024);
            gload16(gb3 + (size_t)t * 128 + i * rstride, (char*)B3s + i * 4096 + wid * 1024);
        }
        __syncthreads();
#pragma unroll
        for (int kk = 0; kk < 2; ++kk) {
            const int sl = ((kk << 2) | g) ^ (li & 7);
            s16x8 aF[4];
#pragma unroll
            for (int m = 0; m < 4; ++m) aF[m] = *(const s16x8*)&As[(wr * 64 + m * 16 + li) * 64 + sl * 8];
            {   // W1 product
                s16x8 bF[4];
#pragma unroll
                for (int n = 0; n < 4; ++n) bF[n] = *(const s16x8*)&B1s[(wc * 64 + n * 16 + li) * 64 + sl * 8];
#pragma unroll
                for (int m = 0; m < 4; ++m)
#pragma unroll
                    for (int n = 0; n < 4; ++n)
                        acc1[m][n] = MFMA(aF[m], bF[n], acc1[m][n]);
            }
            {   // W3 product
                s16x8 bF[4];
#pragma unroll
                for (int n = 0; n < 4; ++n) bF[n] = *(const s16x8*)&B3s[(wc * 64 + n * 16 + li) * 64 + sl * 8];
#pragma unroll
                for (int m = 0; m < 4; ++m)
#pragma unroll
                    for (int n = 0; n < 4; ++n)
                        acc3[m][n] = MFMA(aF[m], bF[n], acc3[m][n]);
            }
        }
        __syncthreads();
    }

#pragma unroll
    for (int m = 0; m < 4; ++m)
#pragma unroll
        for (int n = 0; n < 4; ++n)
#pragma unroll
            for (int r = 0; r < 4; ++r) {
                size_t row = m0 + wr * 64 + m * 16 + g * 4 + r;
                size_t col = n0 + wc * 64 + n * 16 + li;
                float h1 = acc1[m][n][r];
                float h3 = acc3[m][n][r];
                float sg = 1.f / (1.f + __expf(-h1));
                Hout[row * N + col] = f2bf(h1 * sg * h3);
            }
}

// ---------------- RoPE in-place on q and k (strided); q additionally scaled by 0.125
__global__ __launch_bounds__(256) void rope_qk(u16* __restrict__ q, u16* __restrict__ k,
                                               const float* __restrict__ fr, int S) {
    size_t idx = (size_t)blockIdx.x * 256 + threadIdx.x; // over B*T*H*(HD/2)
    int i = (int)(idx & 31);
    int h = (int)((idx >> 5) & 15);
    size_t bt = idx >> 9;             // b*T + t
    int t = (int)(bt & (T_ - 1));
    float2 cs = ((const float2*)fr)[t * 32 + i];
    size_t off = bt * (size_t)S + h * 64 + 2 * i;
    {
        u32* p = (u32*)(q + off);
        u32 w = *p;
        float a = bf2f((u16)(w & 0xffff)), b = bf2f((u16)(w >> 16));
        *p = (u32)f2bf((a * cs.x - b * cs.y) * 0.125f) | ((u32)f2bf((a * cs.y + b * cs.x) * 0.125f) << 16);
    }
    {
        u32* p = (u32*)(k + off);
        u32 w = *p;
        float a = bf2f((u16)(w & 0xffff)), b = bf2f((u16)(w >> 16));
        *p = (u32)f2bf(a * cs.x - b * cs.y) | ((u32)f2bf(a * cs.y + b * cs.x) << 16);
    }
}

// ---------------- V transpose: v[B,Tk,*] (stride S) bf16 -> vT[B,H,HD,Tk] bf16
__global__ __launch_bounds__(256) void vtrans(const u16* __restrict__ v, u16* __restrict__ vT,
                                              int Tk, int S) {
    __shared__ u16 tile[32][34];
    int bh = blockIdx.x;
    int t0 = blockIdx.y * 32, d0 = blockIdx.z * 32;
    int b = bh >> 4, h = bh & 15;
    int tid = threadIdx.x;
    int tx = tid & 31, ty = tid >> 5;
#pragma unroll
    for (int i = 0; i < 4; ++i)
        tile[ty + i * 8][tx] = v[((size_t)b * Tk + t0 + ty + i * 8) * S + h * 64 + d0 + tx];
    __syncthreads();
#pragma unroll
    for (int i = 0; i < 4; ++i)
        vT[((size_t)bh * 64 + d0 + ty + i * 8) * Tk + t0 + tx] = tile[tx][ty + i * 8];
}

// ---------------- online-softmax update + P->bf16 B-fragment pack (shared helper)
__device__ __forceinline__ void sm_pack(const f32x16& s, int hi, float& mr, float& lr,
                                        f32x16& o0, f32x16& o1, s16x8& pf0v, s16x8& pf1v) {
    float bm = fmaxf(fmaxf(fmaxf(s[0], s[1]), fmaxf(s[2], s[3])),
                     fmaxf(fmaxf(s[4], s[5]), fmaxf(s[6], s[7])));
    float bm2 = fmaxf(fmaxf(fmaxf(s[8], s[9]), fmaxf(s[10], s[11])),
                      fmaxf(fmaxf(s[12], s[13]), fmaxf(s[14], s[15])));
    bm = fmaxf(bm, bm2);
    bm = fmaxf(bm, __shfl_xor(bm, 32));
    float mn = fmaxf(mr, bm);
    float sc = __expf(mr - mn);
    mr = mn;
    float p[16];
    float rs = 0.f;
#pragma unroll
    for (int r = 0; r < 16; ++r) { p[r] = __expf(s[r] - mn); rs += p[r]; }
    rs += __shfl_xor(rs, 32);
    lr = lr * sc + rs;
#pragma unroll
    for (int r = 0; r < 16; ++r) { o0[r] *= sc; o1[r] *= sc; }

    u32 pk[8];
#pragma unroll
    for (int i = 0; i < 8; ++i)
        pk[i] = (u32)f2bf(p[2 * i]) | ((u32)f2bf(p[2 * i + 1]) << 16);
    u32 e1 = __shfl_xor(hi ? pk[0] : pk[2], 32);
    u32 e2 = __shfl_xor(hi ? pk[1] : pk[3], 32);
    u32 e3 = __shfl_xor(hi ? pk[4] : pk[6], 32);
    u32 e4 = __shfl_xor(hi ? pk[5] : pk[7], 32);
    union { s16x8 v; u32 w[4]; } pf0, pf1;
    pf0.w[0] = hi ? e1 : pk[0];
    pf0.w[1] = hi ? e2 : pk[1];
    pf0.w[2] = hi ? pk[2] : e1;
    pf0.w[3] = hi ? pk[3] : e2;
    pf1.w[0] = hi ? e3 : pk[4];
    pf1.w[1] = hi ? e4 : pk[5];
    pf1.w[2] = hi ? pk[6] : e3;
    pf1.w[3] = hi ? pk[7] : e4;
    pf0v = pf0.v;
    pf1v = pf1.v;
}

__device__ __forceinline__ void attn_out(u16* ob, const f32x16& o0, const f32x16& o1,
                                         float lr, int hi) {
    float inv = 1.f / lr;
#pragma unroll
    for (int r = 0; r < 16; ++r) {
        int hd = (r & 3) + 8 * (r >> 2) + 4 * hi;
        ob[hd] = f2bf(o0[r] * inv);
        ob[hd + 32] = f2bf(o1[r] * inv);
    }
}

// ---------------- swapped-QK^T 32x32 attention tile (serial, used by cross-attn)
__device__ __forceinline__ void attn32(const u16* __restrict__ qh, const u16* __restrict__ kh,
                                       const u16* __restrict__ vh, u16* __restrict__ oh,
                                       int q0, int nkb, int Tk, int causal, int lq, int hi,
                                       int QS, int KS) {
    const u16* qb = qh + (size_t)(q0 + lq) * QS;
    s16x8 qf[4];
#pragma unroll
    for (int c = 0; c < 4; ++c) qf[c] = *(const s16x8*)&qb[c * 16 + hi * 8];

    f32x16 o0 = {}, o1 = {};
    float mr = -1e30f, lr = 0.f;

    for (int kb = 0; kb < nkb; ++kb) {
        const int ks = kb * 32;
        f32x16 s = {};
        const u16* kp = kh + (size_t)(ks + lq) * KS + hi * 8;
#pragma unroll
        for (int c = 0; c < 4; ++c) {
            s16x8 kf = *(const s16x8*)&kp[c * 16];
            s = MFMA32(kf, qf[c], s);
        }
        if (causal && kb == nkb - 1) {
#pragma unroll
            for (int r = 0; r < 16; ++r) {
                int kl = (r & 3) + 8 * (r >> 2) + 4 * hi;
                if (kl > lq) s[r] = -1e30f;
            }
        }
        s16x8 pf0, pf1;
        sm_pack(s, hi, mr, lr, o0, o1, pf0, pf1);

        const u16* v0 = vh + (size_t)lq * Tk + ks + hi * 8;
        const u16* v1 = vh + (size_t)(32 + lq) * Tk + ks + hi * 8;
        o0 = MFMA32(*(const s16x8*)&v0[0],  pf0, o0);
        o0 = MFMA32(*(const s16x8*)&v0[16], pf1, o0);
        o1 = MFMA32(*(const s16x8*)&v1[0],  pf0, o1);
        o1 = MFMA32(*(const s16x8*)&v1[16], pf1, o1);
    }
    attn_out(oh + (size_t)(q0 + lq) * D_, o0, o1, lr, hi);
}

// ---------------- FUSED paired-tile causal attention: one wave = tiles (p, 63-p)
// over the SAME k range. K/V fragments loaded ONCE per kb serve both tiles;
// tile-B's QK MFMAs overlap tile-A's softmax VALU (and PV_A overlaps softmax_B)
// via the independent MFMA/VALU pipes (T15/m114 mechanism).
__global__ __launch_bounds__(256) void attn_causal_pair(const u16* __restrict__ q, const u16* __restrict__ k,
                                                        const u16* __restrict__ vT, u16* __restrict__ o,
                                                        int Tq, int Tk, int QS, int KS) {
    const int lane = threadIdx.x & 63, wid = threadIdx.x >> 6;
    const int lq = lane & 31, hi = lane >> 5;
    const int ntile = Tq / 32;            // 64
    const int ppb = (ntile / 2) / 4;      // 8 pairs per block
    const int bh = blockIdx.x / ppb;
    const int p = (blockIdx.x % ppb) * 4 + wid;
    const int b = bh >> 4, h = bh & 15;

    const u16* qh = q + ((size_t)b * Tq) * QS + h * 64;
    const u16* kh = k + ((size_t)b * Tk) * KS + h * 64;
    const u16* vh = vT + ((size_t)bh * 64) * Tk;
    u16* oh = o + ((size_t)b * Tq) * D_ + h * 64;

    const int tA = p, tB = ntile - 1 - p;      // tA <= 31 < tB always
    const int q0A = tA * 32, q0B = tB * 32;

    s16x8 qfA[4], qfB[4];
    {
        const u16* qbA = qh + (size_t)(q0A + lq) * QS;
        const u16* qbB = qh + (size_t)(q0B + lq) * QS;
#pragma unroll
        for (int c = 0; c < 4; ++c) {
            qfA[c] = *(const s16x8*)&qbA[c * 16 + hi * 8];
            qfB[c] = *(const s16x8*)&qbB[c * 16 + hi * 8];
        }
    }

    f32x16 oA0 = {}, oA1 = {}, oB0 = {}, oB1 = {};
    float mrA = -1e30f, lrA = 0.f, mrB = -1e30f, lrB = 0.f;

    for (int kb = 0; kb <= tB; ++kb) {
        const int ks = kb * 32;
        const bool doA = (kb <= tA);
        const u16* kp = kh + (size_t)(ks + lq) * KS + hi * 8;
        s16x8 kf[4];
#pragma unroll
        for (int c = 0; c < 4; ++c) kf[c] = *(const s16x8*)&kp[c * 16];

        f32x16 sA = {}, sB = {};
        if (doA) {
#pragma unroll
            for (int c = 0; c < 4; ++c) sA = MFMA32(kf[c], qfA[c], sA);
        }
#pragma unroll
        for (int c = 0; c < 4; ++c) sB = MFMA32(kf[c], qfB[c], sB);

        // shared V fragments
        const u16* v0p = vh + (size_t)lq * Tk + ks + hi * 8;
        const u16* v1p = vh + (size_t)(32 + lq) * Tk + ks + hi * 8;
        s16x8 v00 = *(const s16x8*)&v0p[0],  v01 = *(const s16x8*)&v0p[16];
        s16x8 v10 = *(const s16x8*)&v1p[0],  v11 = *(const s16x8*)&v1p[16];

        if (doA) {
            if (kb == tA) {
#pragma unroll
                for (int r = 0; r < 16; ++r) {
                    int kl = (r & 3) + 8 * (r >> 2) + 4 * hi;
                    if (kl > lq) sA[r] = -1e30f;
                }
            }
            s16x8 pf0, pf1;
            sm_pack(sA, hi, mrA, lrA, oA0, oA1, pf0, pf1);   // VALU; overlaps sB MFMAs
            oA0 = MFMA32(v00, pf0, oA0);
            oA0 = MFMA32(v01, pf1, oA0);
            oA1 = MFMA32(v10, pf0, oA1);
            oA1 = MFMA32(v11, pf1, oA1);
        }
        {
            if (kb == tB) {
#pragma unroll
                for (int r = 0; r < 16; ++r) {
                    int kl = (r & 3) + 8 * (r >> 2) + 4 * hi;
                    if (kl > lq) sB[r] = -1e30f;
                }
            }
            s16x8 pf0, pf1;
            sm_pack(sB, hi, mrB, lrB, oB0, oB1, pf0, pf1);   // VALU; overlaps PV_A MFMAs
            oB0 = MFMA32(v00, pf0, oB0);
            oB0 = MFMA32(v01, pf1, oB0);
            oB1 = MFMA32(v10, pf0, oB1);
            oB1 = MFMA32(v11, pf1, oB1);
        }
    }

    attn_out(oh + (size_t)(q0A + lq) * D_, oA0, oA1, lrA, hi);
    attn_out(oh + (size_t)(q0B + lq) * D_, oB0, oB1, lrB, hi);
}

// ---------------- non-causal cross-attention: one wave per 32-row q-tile
__global__ __launch_bounds__(256) void attn_plain32(const u16* __restrict__ q, const u16* __restrict__ k,
                                                    const u16* __restrict__ vT, u16* __restrict__ o,
                                                    int Tq, int Tk, int QS, int KS) {
    const int lane = threadIdx.x & 63, wid = threadIdx.x >> 6;
    const int lq = lane & 31, hi = lane >> 5;
    const int tpb = (Tq / 32) / 4;        // 16 tiles per block
    const int bh = blockIdx.x / tpb;
    const int qt = (blockIdx.x % tpb) * 4 + wid;
    const int b = bh >> 4, h = bh & 15;

    const u16* qh = q + ((size_t)b * Tq) * QS + h * 64;
    const u16* kh = k + ((size_t)b * Tk) * KS + h * 64;
    const u16* vh = vT + ((size_t)bh * 64) * Tk;
    u16* oh = o + ((size_t)b * Tq) * D_ + h * 64;

    attn32(qh, kh, vh, oh, qt * 32, Tk / 32, Tk, 0, lq, hi, QS, KS);
}

// ---------------- fused residual add + RMSNorm: one WAVE per row, 4x float4 per lane.
// xb is bf16 (GEMM epilogue writes mode 1): halves the non-residual stream.
__global__ __launch_bounds__(256) void addnorm(const float* __restrict__ xa, const u16* __restrict__ xb,
                                               const float* __restrict__ gg, float* __restrict__ fo,
                                               u16* __restrict__ bo) {
    int row = blockIdx.x * 4 + (threadIdx.x >> 6);
    int lane = threadIdx.x & 63;
    const float4* pa = (const float4*)(xa + (size_t)row * D_);
    const u64* pb = (const u64*)(xb + (size_t)row * D_);
    float4 v[4];
    float ss = 0.f;
#pragma unroll
    for (int j = 0; j < 4; ++j) {
        float4 a = pa[lane + 64 * j];
        u64 bw = pb[lane + 64 * j];
        v[j].x = a.x + bf2f((u16)(bw));
        v[j].y = a.y + bf2f((u16)(bw >> 16));
        v[j].z = a.z + bf2f((u16)(bw >> 32));
        v[j].w = a.w + bf2f((u16)(bw >> 48));
        ss += v[j].x * v[j].x + v[j].y * v[j].y + v[j].z * v[j].z + v[j].w * v[j].w;
    }
    ss += __shfl_xor(ss, 1);
    ss += __shfl_xor(ss, 2);
    ss += __shfl_xor(ss, 4);
    ss += __shfl_xor(ss, 8);
    ss += __shfl_xor(ss, 16);
    ss += __shfl_xor(ss, 32);
    float s = rsqrtf(ss * (1.0f / D_) + 1e-6f);
#pragma unroll
    for (int j = 0; j < 4; ++j) {
        float4 gv = ((const float4*)gg)[lane + 64 * j];
        float yx = v[j].x * s * gv.x, yy = v[j].y * s * gv.y;
        float yz = v[j].z * s * gv.z, yw = v[j].w * s * gv.w;
        if (fo) {
            float4 o4; o4.x = yx; o4.y = yy; o4.z = yz; o4.w = yw;
            ((float4*)(fo + (size_t)row * D_))[lane + 64 * j] = o4;
        }
        if (bo) {
            u64 pk = (u64)f2bf(yx) | ((u64)f2bf(yy) << 16) | ((u64)f2bf(yz) << 32) | ((u64)f2bf(yw) << 48);
            ((u64*)(bo + (size_t)row * D_))[lane + 64 * j] = pk;
        }
    }
}

extern "C" void kernel_launch(void* const* d_in, const int* in_sizes, int n_in,
                              void* d_out, int out_size, void* d_ws, size_t ws_size,
                              hipStream_t stream) {
    const float* x    = (const float*)d_in[0];
    const float* mem  = (const float*)d_in[1];
    const float* fr   = (const float*)d_in[2];
    const float* wsaq = (const float*)d_in[4];
    const float* wsak = (const float*)d_in[5];
    const float* wsav = (const float*)d_in[6];
    const float* wsao = (const float*)d_in[7];
    const float* wcaq = (const float*)d_in[8];
    const float* wcak = (const float*)d_in[9];
    const float* wcav = (const float*)d_in[10];
    const float* wcao = (const float*)d_in[11];
    const float* w1   = (const float*)d_in[12];
    const float* w3   = (const float*)d_in[13];
    const float* w2   = (const float*)d_in[14];
    const float* g_sa = (const float*)d_in[15];
    const float* g_ca = (const float*)d_in[16];
    const float* g_ff = (const float*)d_in[17];
    float* outF = (float*)d_out;

    char* p = (char*)d_ws;
    auto alloc = [&](size_t bytes) { char* r = p; p += (bytes + 255) & ~(size_t)255; return r; };
    const size_t DD2 = (size_t)1024 * 1024 * 2;
    u16* wqkvT = (u16*)alloc(3 * DD2);                 // [3072][1024] fused q|k|v
    u16* saoT  = (u16*)alloc(DD2);
    u16* caqT  = (u16*)alloc(DD2);
    u16* wkvT  = (u16*)alloc(2 * DD2);                 // [2048][1024] fused k|v (CA)
    u16* caoT  = (u16*)alloc(DD2);
    u16* w1T   = (u16*)alloc((size_t)HIDP_ * 1024 * 2);
    u16* w3T   = (u16*)alloc((size_t)HIDP_ * 1024 * 2);
    u16* w2T   = (u16*)alloc((size_t)1024 * HIDP_ * 2);
    u16* Ab    = (u16*)alloc((size_t)8192 * 1024 * 2);
    u16* memb  = (u16*)alloc((size_t)2048 * 1024 * 2);
    char* qkvRaw = alloc((size_t)8192 * 3072 * 2);     // SA fused q|k|v [8192][3072]
    u16* qkvb = (u16*)qkvRaw;
    u16* kvb  = (u16*)qkvRaw;                          // CA k|v [2048][2048] (aliased; used after SA)
    u16* caqb = (u16*)(qkvRaw + (size_t)25165824);     // CA q [8192][1024] (aliased upper region)
    u16* vtb  = (u16*)alloc((size_t)8192 * 1024 * 2);
    u16* ob   = (u16*)alloc((size_t)8192 * 1024 * 2);
    u16* Pb   = (u16*)alloc((size_t)8192 * 1024 * 2);  // bf16 GEMM->addnorm intermediate
    float* Rf = (float*)alloc((size_t)8192 * 1024 * 4);
    u16* Hb   = (u16*)alloc((size_t)8192 * HIDP_ * 2);

    dim3 blk(256);

    // weight prep (fused QKV rows: q 0-1023 | k 1024-2047 | v 2048-3071)
    wt_cast<<<dim3(32, 32), blk, 0, stream>>>(wsaq, wqkvT,               1024, 1024, 1024, 1024);
    wt_cast<<<dim3(32, 32), blk, 0, stream>>>(wsak, wqkvT + 1024 * 1024, 1024, 1024, 1024, 1024);
    wt_cast<<<dim3(32, 32), blk, 0, stream>>>(wsav, wqkvT + 2048 * 1024, 1024, 1024, 1024, 1024);
    wt_cast<<<dim3(32, 32), blk, 0, stream>>>(wsao, saoT, 1024, 1024, 1024, 1024);
    wt_cast<<<dim3(32, 32), blk, 0, stream>>>(wcaq, caqT, 1024, 1024, 1024, 1024);
    wt_cast<<<dim3(32, 32), blk, 0, stream>>>(wcak, wkvT,               1024, 1024, 1024, 1024);
    wt_cast<<<dim3(32, 32), blk, 0, stream>>>(wcav, wkvT + 1024 * 1024, 1024, 1024, 1024, 1024);
    wt_cast<<<dim3(32, 32), blk, 0, stream>>>(wcao, caoT, 1024, 1024, 1024, 1024);
    wt_cast<<<dim3(88, 32), blk, 0, stream>>>(w1, w1T, 1024, HID_, 1024, HIDP_);
    wt_cast<<<dim3(88, 32), blk, 0, stream>>>(w3, w3T, 1024, HID_, 1024, HIDP_);
    wt_cast<<<dim3(32, 88), blk, 0, stream>>>(w2, w2T, HID_, 1024, HIDP_, 1024);

    cast_bf16<<<8192, blk, 0, stream>>>(x, Ab, 2097152);
    cast_bf16<<<2048, blk, 0, stream>>>(mem, memb, 524288);

    // ---- self-attention (fused QKV projection, N=3072)
    gemm_bf16<<<1536, blk, 0, stream>>>(Ab, wqkvT, qkvb, nullptr, 8192, 3072, 1024, 1, 1536);
    rope_qk<<<16384, blk, 0, stream>>>(qkvb, qkvb + 1024, fr, 3072);
    vtrans<<<dim3(64, 64, 2), blk, 0, stream>>>(qkvb + 2048, vtb, 2048, 3072);
    attn_causal_pair<<<512, blk, 0, stream>>>(qkvb, qkvb + 1024, vtb, ob, 2048, 2048, 3072, 3072);
    gemm_bf16<<<512, blk, 0, stream>>>(ob, saoT, Pb, nullptr, 8192, 1024, 1024, 1, 512);
    addnorm<<<2048, blk, 0, stream>>>(x, Pb, g_sa, Rf, Ab);

    // ---- cross-attention (fused KV projection, N=2048; q scaled via mode 4)
    gemm_bf16<<<512, blk, 0, stream>>>(Ab, caqT, caqb, nullptr, 8192, 1024, 1024, 4, 512);
    gemm_bf16<<<256, blk, 0, stream>>>(memb, wkvT, kvb, nullptr, 2048, 2048, 1024, 1, 256);
    vtrans<<<dim3(64, 16, 2), blk, 0, stream>>>(kvb + 1024, vtb, 512, 2048);
    attn_plain32<<<1024, blk, 0, stream>>>(caqb, kvb, vtb, ob, 2048, 512, 1024, 2048);
    gemm_bf16<<<512, blk, 0, stream>>>(ob, caoT, Pb, nullptr, 8192, 1024, 1024, 1, 512);
    addnorm<<<2048, blk, 0, stream>>>(Rf, Pb, g_ca, Rf, Ab);

    // ---- FFN (SwiGLU): fused w1+w3 -> H, then down-proj
    gemm_w13<<<1408, blk, 0, stream>>>(Ab, w1T, w3T, Hb, 8192, HIDP_, 1024, 1408);
    gemm_bf16<<<512, blk, 0, stream>>>(Hb, w2T, Pb, nullptr, 8192, 1024, HIDP_, 1, 512);
    addnorm<<<2048, blk, 0, stream>>>(Rf, Pb, g_ff, outF, nullptr);
}